// Round 2
// baseline (3103.058 us; speedup 1.0000x reference)
//
#include <hip/hip_runtime.h>
#include <hip/hip_bf16.h>

// ---------------------------------------------------------------------------
// DepthDeltaNetDecoderLayer: B=1, T=2048, D=1024, H=16, DK=DV=64, FF=4096
// Round 1: precision fix — split-bf16 (hi+lo) GEMM for the fused qkv/gate/g/b
// projection so the recurrent scan sees ~f32-accurate inputs. Scan stays f32,
// 1 wave/head (chunked MFMA version planned next round).
// ---------------------------------------------------------------------------

#define T_SEQ 2048
#define D_MODEL 1024
#define NH 16
#define DK 64
#define DV 64
#define FF 4096
#define NQKV 4224   // q(1024) k(1024) v(1024) gate(1024) g(16@4096) b(16@4112) pad->4224

typedef __bf16 bf16x8 __attribute__((ext_vector_type(8)));
typedef float  fx4    __attribute__((ext_vector_type(4)));

// ---------------------------------------------------------------- rope table
__global__ void rope_table_kernel(float2* __restrict__ cs) {
    int idx = blockIdx.x * 256 + threadIdx.x;      // t*32 + i, 65536 total
    int t = idx >> 5, i = idx & 31;
    float freq = (float)t * powf(10000.f, -(float)i / 32.f);
    cs[idx] = make_float2(cosf(freq), sinf(freq));
}

// --------------------------------------- row rmsnorm -> bf16 hi + bf16 lo
__global__ __launch_bounds__(256) void rmsnorm_split_kernel(
    const float* __restrict__ in, const float* __restrict__ w,
    __hip_bfloat16* __restrict__ hi, __hip_bfloat16* __restrict__ lo) {
    int t = blockIdx.x;
    int d = threadIdx.x * 4;
    const float4 v = *(const float4*)(in + (size_t)t * D_MODEL + d);
    float ss = v.x * v.x + v.y * v.y + v.z * v.z + v.w * v.w;
#pragma unroll
    for (int m = 32; m; m >>= 1) ss += __shfl_xor(ss, m, 64);
    __shared__ float wsum[4];
    if ((threadIdx.x & 63) == 0) wsum[threadIdx.x >> 6] = ss;
    __syncthreads();
    float tot = wsum[0] + wsum[1] + wsum[2] + wsum[3];
    float sc = rsqrtf(tot * (1.f / 1024.f) + 1e-6f);
    const float4 wv = *(const float4*)(w + d);
    float xs[4] = {v.x * sc * wv.x, v.y * sc * wv.y, v.z * sc * wv.z, v.w * sc * wv.w};
    __hip_bfloat16* hp = hi + (size_t)t * D_MODEL + d;
    __hip_bfloat16* lp = lo + (size_t)t * D_MODEL + d;
#pragma unroll
    for (int j = 0; j < 4; ++j) {
        __hip_bfloat16 h = __float2bfloat16(xs[j]);
        hp[j] = h;
        lp[j] = __float2bfloat16(xs[j] - __bfloat162float(h));
    }
}

// ------------------------------------------- W (KxN f32) -> Wt (Npad x K bf16)
__global__ void transpose_bf16_kernel(const float* __restrict__ W,
                                      __hip_bfloat16* __restrict__ Wt,
                                      int K, int N, int Npad) {
    __shared__ float tile[32][33];
    int k0 = blockIdx.x * 32, n0 = blockIdx.y * 32;
    int tx = threadIdx.x, ty = threadIdx.y;   // (32,8)
#pragma unroll
    for (int i = 0; i < 32; i += 8) {
        int n = n0 + tx;
        tile[ty + i][tx] = (n < N) ? W[(size_t)(k0 + ty + i) * N + n] : 0.f;
    }
    __syncthreads();
#pragma unroll
    for (int i = 0; i < 32; i += 8) {
        int n = n0 + ty + i;
        if (n < Npad) Wt[(size_t)n * K + k0 + tx] = __float2bfloat16(tile[tx][ty + i]);
    }
}

// ---------------------- W (KxN f32) -> Wt_hi, Wt_lo (Npad x K bf16 each)
__global__ void transpose_split_kernel(const float* __restrict__ W,
                                       __hip_bfloat16* __restrict__ Wt_hi,
                                       __hip_bfloat16* __restrict__ Wt_lo,
                                       int K, int N, int Npad) {
    __shared__ float tile[32][33];
    int k0 = blockIdx.x * 32, n0 = blockIdx.y * 32;
    int tx = threadIdx.x, ty = threadIdx.y;   // (32,8)
#pragma unroll
    for (int i = 0; i < 32; i += 8) {
        int n = n0 + tx;
        tile[ty + i][tx] = (n < N) ? W[(size_t)(k0 + ty + i) * N + n] : 0.f;
    }
    __syncthreads();
#pragma unroll
    for (int i = 0; i < 32; i += 8) {
        int n = n0 + ty + i;
        if (n < Npad) {
            float x = tile[tx][ty + i];
            __hip_bfloat16 h = __float2bfloat16(x);
            Wt_hi[(size_t)n * K + k0 + tx] = h;
            Wt_lo[(size_t)n * K + k0 + tx] = __float2bfloat16(x - __bfloat162float(h));
        }
    }
}

// ------------------------------------------------------------------- GEMM
// A: MxK bf16 row-major; Bt: NxK bf16 row-major (B transposed); C: MxN.
// 128x128 tile, BK=32, 4 waves, each wave 64x64 (4x4 frags of 16x16x32 MFMA).
template <bool OUT_BF16>
__global__ __launch_bounds__(256) void gemm_bt(
    const __hip_bfloat16* __restrict__ A, const __hip_bfloat16* __restrict__ Bt,
    void* __restrict__ Cout, int M, int N, int K) {
    __shared__ short sA[128 * 32];
    __shared__ short sB[128 * 32];
    const int tid = threadIdx.x;
    const int w = tid >> 6, lane = tid & 63;
    const int bn0 = blockIdx.x * 128, bm0 = blockIdx.y * 128;
    const int wr = w >> 1, wc = w & 1;

    fx4 acc[4][4];
#pragma unroll
    for (int m = 0; m < 4; ++m)
#pragma unroll
        for (int n = 0; n < 4; ++n) acc[m][n] = {0.f, 0.f, 0.f, 0.f};

    for (int k0 = 0; k0 < K; k0 += 32) {
        __syncthreads();
#pragma unroll
        for (int i = 0; i < 2; ++i) {
            int c = i * 256 + tid;          // chunk of 16B; 512 chunks per tile
            int r = c >> 2, kk = (c & 3) * 8;
            int4 va = *(const int4*)(A + (size_t)(bm0 + r) * K + k0 + kk);
            *(int4*)(sA + c * 8) = va;
            int4 vb = *(const int4*)(Bt + (size_t)(bn0 + r) * K + k0 + kk);
            *(int4*)(sB + c * 8) = vb;
        }
        __syncthreads();
        bf16x8 af[4], bfv[4];
#pragma unroll
        for (int m = 0; m < 4; ++m)
            af[m] = *(const bf16x8*)(sA + (wr * 64 + m * 16 + (lane & 15)) * 32 + (lane >> 4) * 8);
#pragma unroll
        for (int n = 0; n < 4; ++n)
            bfv[n] = *(const bf16x8*)(sB + (wc * 64 + n * 16 + (lane & 15)) * 32 + (lane >> 4) * 8);
#pragma unroll
        for (int m = 0; m < 4; ++m)
#pragma unroll
            for (int n = 0; n < 4; ++n)
                acc[m][n] = __builtin_amdgcn_mfma_f32_16x16x32_bf16(af[m], bfv[n], acc[m][n], 0, 0, 0);
    }
    // epilogue: C/D layout col = lane&15, row = (lane>>4)*4 + j
#pragma unroll
    for (int m = 0; m < 4; ++m) {
        int row = bm0 + wr * 64 + m * 16 + (lane >> 4) * 4;
#pragma unroll
        for (int n = 0; n < 4; ++n) {
            int col = bn0 + wc * 64 + n * 16 + (lane & 15);
#pragma unroll
            for (int j = 0; j < 4; ++j) {
                float val = acc[m][n][j];
                if (OUT_BF16)
                    ((__hip_bfloat16*)Cout)[(size_t)(row + j) * N + col] = __float2bfloat16(val);
                else
                    ((float*)Cout)[(size_t)(row + j) * N + col] = val;
            }
        }
    }
}

// ------------------------------------- split-precision GEMM (3 bf16 products)
// C = Ah@Bh + Ah@Bl + Al@Bh  (~f32-accurate). f32 out.
__global__ __launch_bounds__(256) void gemm_bt_split(
    const __hip_bfloat16* __restrict__ Ah, const __hip_bfloat16* __restrict__ Al,
    const __hip_bfloat16* __restrict__ Bth, const __hip_bfloat16* __restrict__ Btl,
    float* __restrict__ Cout, int M, int N, int K) {
    __shared__ short sAh[128 * 32];
    __shared__ short sAl[128 * 32];
    __shared__ short sBh[128 * 32];
    __shared__ short sBl[128 * 32];
    const int tid = threadIdx.x;
    const int w = tid >> 6, lane = tid & 63;
    const int bn0 = blockIdx.x * 128, bm0 = blockIdx.y * 128;
    const int wr = w >> 1, wc = w & 1;

    fx4 acc[4][4];
#pragma unroll
    for (int m = 0; m < 4; ++m)
#pragma unroll
        for (int n = 0; n < 4; ++n) acc[m][n] = {0.f, 0.f, 0.f, 0.f};

    for (int k0 = 0; k0 < K; k0 += 32) {
        __syncthreads();
#pragma unroll
        for (int i = 0; i < 2; ++i) {
            int c = i * 256 + tid;
            int r = c >> 2, kk = (c & 3) * 8;
            size_t ga = (size_t)(bm0 + r) * K + k0 + kk;
            size_t gb = (size_t)(bn0 + r) * K + k0 + kk;
            *(int4*)(sAh + c * 8) = *(const int4*)(Ah + ga);
            *(int4*)(sAl + c * 8) = *(const int4*)(Al + ga);
            *(int4*)(sBh + c * 8) = *(const int4*)(Bth + gb);
            *(int4*)(sBl + c * 8) = *(const int4*)(Btl + gb);
        }
        __syncthreads();
        bf16x8 ah[4], al[4], bh[4], bl[4];
#pragma unroll
        for (int m = 0; m < 4; ++m) {
            int off = (wr * 64 + m * 16 + (lane & 15)) * 32 + (lane >> 4) * 8;
            ah[m] = *(const bf16x8*)(sAh + off);
            al[m] = *(const bf16x8*)(sAl + off);
        }
#pragma unroll
        for (int n = 0; n < 4; ++n) {
            int off = (wc * 64 + n * 16 + (lane & 15)) * 32 + (lane >> 4) * 8;
            bh[n] = *(const bf16x8*)(sBh + off);
            bl[n] = *(const bf16x8*)(sBl + off);
        }
#pragma unroll
        for (int m = 0; m < 4; ++m)
#pragma unroll
            for (int n = 0; n < 4; ++n) {
                acc[m][n] = __builtin_amdgcn_mfma_f32_16x16x32_bf16(ah[m], bh[n], acc[m][n], 0, 0, 0);
                acc[m][n] = __builtin_amdgcn_mfma_f32_16x16x32_bf16(ah[m], bl[n], acc[m][n], 0, 0, 0);
                acc[m][n] = __builtin_amdgcn_mfma_f32_16x16x32_bf16(al[m], bh[n], acc[m][n], 0, 0, 0);
            }
    }
#pragma unroll
    for (int m = 0; m < 4; ++m) {
        int row = bm0 + wr * 64 + m * 16 + (lane >> 4) * 4;
#pragma unroll
        for (int n = 0; n < 4; ++n) {
            int col = bn0 + wc * 64 + n * 16 + (lane & 15);
#pragma unroll
            for (int j = 0; j < 4; ++j)
                Cout[(size_t)(row + j) * N + col] = acc[m][n][j];
        }
    }
}

// --------------------------------------------- RoPE + L2-normalize q,k in place
__global__ __launch_bounds__(256) void rope_kernel(float* __restrict__ X1,
                                                   const float2* __restrict__ cs) {
    int w = threadIdx.x >> 6, lane = threadIdx.x & 63;
    int p = blockIdx.x * 4 + w;            // (t,h) pair, 32768 total
    int t = p >> 4, h = p & 15;
    float2 c = cs[t * 32 + (lane & 31)];
#pragma unroll
    for (int which = 0; which < 2; ++which) {
        float* base = X1 + (size_t)t * NQKV + which * 1024 + h * 64;
        float x = base[lane];
        float xo = __shfl(x, lane ^ 32, 64);
        float r = (lane < 32) ? -xo : xo;
        float y = x * c.x + r * c.y;
        float ss = y * y;
#pragma unroll
        for (int m = 32; m; m >>= 1) ss += __shfl_xor(ss, m, 64);
        base[lane] = y * rsqrtf(ss + 1e-12f);
    }
}

// ------------------------------------------------- sequential delta-rule scan
// One wave per head. Lane = output column v of S (DKxDV). S[j] = S[j][lane].
__global__ __launch_bounds__(64) void scan_kernel(const float* __restrict__ X1,
                                                  float* __restrict__ o) {
    const int h = blockIdx.x;
    const int lane = threadIdx.x;
    float S[64];
#pragma unroll
    for (int j = 0; j < 64; ++j) S[j] = 0.f;
    const float* base_q = X1 + h * 64 + lane;
    const float* base_k = base_q + 1024;
    const float* base_v = base_q + 2048;
    const float* base_g = X1 + 4096 + h;
    float qv = base_q[0], kv = base_k[0], vv = base_v[0];
    float ga = base_g[0], gb = base_g[16];
    for (int t = 0; t < T_SEQ; ++t) {
        float qn = 0.f, kn = 0.f, vn = 0.f, gan = 0.f, gbn = 0.f;
        if (t < T_SEQ - 1) {                 // prefetch next step
            size_t off = (size_t)(t + 1) * NQKV;
            qn = base_q[off]; kn = base_k[off]; vn = base_v[off];
            gan = base_g[off]; gbn = base_g[off + 16];
        }
        float a = 1.f / (1.f + expf(-ga));
        float b = 1.f / (1.f + expf(-gb));
        // 4-way split accumulators to break fmaf dependency chains
        float o0 = 0.f, o1 = 0.f, o2 = 0.f, o3 = 0.f;
        float s0 = 0.f, s1 = 0.f, s2 = 0.f, s3 = 0.f;
#pragma unroll
        for (int j = 0; j < 64; j += 4) {
            float qb0 = __shfl(qv, j, 64),     kb0 = __shfl(kv, j, 64);
            float qb1 = __shfl(qv, j + 1, 64), kb1 = __shfl(kv, j + 1, 64);
            float qb2 = __shfl(qv, j + 2, 64), kb2 = __shfl(kv, j + 2, 64);
            float qb3 = __shfl(qv, j + 3, 64), kb3 = __shfl(kv, j + 3, 64);
            o0 = fmaf(qb0, S[j], o0);     s0 = fmaf(kb0, S[j], s0);
            o1 = fmaf(qb1, S[j + 1], o1); s1 = fmaf(kb1, S[j + 1], s1);
            o2 = fmaf(qb2, S[j + 2], o2); s2 = fmaf(kb2, S[j + 2], s2);
            o3 = fmaf(qb3, S[j + 3], o3); s3 = fmaf(kb3, S[j + 3], s3);
        }
        float oacc = (o0 + o1) + (o2 + o3);
        float sk = (s0 + s1) + (s2 + s3);
        float bd = b * (vv - sk);
#pragma unroll
        for (int j = 0; j < 64; ++j) {
            float kb = __shfl(kv, j, 64);
            S[j] = fmaf(a, S[j], bd * kb);
        }
        o[(size_t)t * D_MODEL + h * 64 + lane] = oacc;
        qv = qn; kv = kn; vv = vn; ga = gan; gb = gbn;
    }
}

// -------------------------------------- o_norm(o) * silu(gate) -> bf16
__global__ __launch_bounds__(256) void o_gate_kernel(const float* __restrict__ o,
                                                     const float* __restrict__ X1,
                                                     const float* __restrict__ onw,
                                                     __hip_bfloat16* __restrict__ out) {
    int w = threadIdx.x >> 6, lane = threadIdx.x & 63;
    int p = blockIdx.x * 4 + w;
    int t = p >> 4, h = p & 15;
    float ov = o[(size_t)t * D_MODEL + h * 64 + lane];
    float ss = ov * ov;
#pragma unroll
    for (int m = 32; m; m >>= 1) ss += __shfl_xor(ss, m, 64);
    float on = ov * rsqrtf(ss * (1.f / 64.f) + 1e-6f) * onw[lane];
    float g = X1[(size_t)t * NQKV + 3072 + h * 64 + lane];
    float sg = g / (1.f + expf(-g));
    out[(size_t)t * D_MODEL + h * 64 + lane] = __float2bfloat16(on * sg);
}

// ---------------------------- h = hidden + attn (in place); ybf = rmsnorm(h)
__global__ __launch_bounds__(256) void add_rmsnorm_kernel(
    const float* __restrict__ hidden, float* __restrict__ acc,
    const float* __restrict__ w, __hip_bfloat16* __restrict__ out) {
    int t = blockIdx.x;
    int d = threadIdx.x * 4;
    float4 a = *(const float4*)(acc + (size_t)t * D_MODEL + d);
    float4 hd = *(const float4*)(hidden + (size_t)t * D_MODEL + d);
    float4 h4 = make_float4(a.x + hd.x, a.y + hd.y, a.z + hd.z, a.w + hd.w);
    *(float4*)(acc + (size_t)t * D_MODEL + d) = h4;
    float ss = h4.x * h4.x + h4.y * h4.y + h4.z * h4.z + h4.w * h4.w;
#pragma unroll
    for (int m = 32; m; m >>= 1) ss += __shfl_xor(ss, m, 64);
    __shared__ float wsum[4];
    if ((threadIdx.x & 63) == 0) wsum[threadIdx.x >> 6] = ss;
    __syncthreads();
    float tot = wsum[0] + wsum[1] + wsum[2] + wsum[3];
    float sc = rsqrtf(tot * (1.f / 1024.f) + 1e-6f);
    const float4 wv = *(const float4*)(w + d);
    __hip_bfloat16* op = out + (size_t)t * D_MODEL + d;
    op[0] = __float2bfloat16(h4.x * sc * wv.x);
    op[1] = __float2bfloat16(h4.y * sc * wv.y);
    op[2] = __float2bfloat16(h4.z * sc * wv.z);
    op[3] = __float2bfloat16(h4.w * sc * wv.w);
}

// ---------------------------------------------- m = silu(G) * U (bf16 in/out)
__global__ __launch_bounds__(256) void silu_mul_kernel(const __hip_bfloat16* __restrict__ GU,
                                                       __hip_bfloat16* __restrict__ m) {
    size_t i = (size_t)blockIdx.x * 256 + threadIdx.x;   // 2048*4096
    size_t t = i >> 12, j = i & 4095;
    float g = __bfloat162float(GU[t * 8192 + j]);
    float u = __bfloat162float(GU[t * 8192 + 4096 + j]);
    m[i] = __float2bfloat16(u * g / (1.f + expf(-g)));
}

// ----------------------------------------------------------- out += h
__global__ __launch_bounds__(256) void final_add_kernel(float* __restrict__ out,
                                                        const float* __restrict__ h) {
    size_t i = (size_t)blockIdx.x * 256 + threadIdx.x;
    out[i] += h[i];
}

// ---------------------------------------------------------------------------
extern "C" void kernel_launch(void* const* d_in, const int* in_sizes, int n_in,
                              void* d_out, int out_size, void* d_ws, size_t ws_size,
                              hipStream_t stream) {
    (void)in_sizes; (void)n_in; (void)out_size; (void)ws_size;
    const float* hidden     = (const float*)d_in[0];
    const float* norm1_w    = (const float*)d_in[1];
    const float* q_w        = (const float*)d_in[2];
    const float* k_w        = (const float*)d_in[3];
    const float* v_w        = (const float*)d_in[4];
    const float* g_w        = (const float*)d_in[5];
    const float* b_w        = (const float*)d_in[6];
    const float* gate_w     = (const float*)d_in[7];
    const float* o_norm_w   = (const float*)d_in[8];
    const float* o_w        = (const float*)d_in[9];
    const float* norm2_w    = (const float*)d_in[10];
    const float* mlp_gate_w = (const float*)d_in[11];
    const float* mlp_up_w   = (const float*)d_in[12];
    const float* mlp_down_w = (const float*)d_in[13];

    char* ws = (char*)d_ws;
    // workspace layout (bytes); total 96,468,992 (~92 MiB), timeline-reused:
    const size_t OFF_WT_QKVG = 0;          // hi: 4224*1024*2 = 8,650,752
    const size_t OFF_WT_O    = 8650752;    // 1024*1024*2 = 2,097,152
    const size_t OFF_WT_GU   = 10747904;   // 8192*1024*2 = 16,777,216
    const size_t OFF_WT_DOWN = 27525120;   // 1024*4096*2 = 8,388,608
    const size_t OFF_X1      = 35913728;   // 2048*4224*4 = 34,603,008 (later GU bf16)
    const size_t OFF_R1      = 70516736;   // 8,650,752: wt_qkvg_lo -> o_buf -> mbf[0:]
    const size_t OFF_ATTN    = 79167488;   // 4,194,304: attn_bf -> mbf part
    const size_t OFF_YBF     = 83361792;   // 4,194,304: ybf -> mbf part (mbf = 16,777,216 <= 17,039,360)
    const size_t OFF_XHI     = 87556096;   // 4,194,304: xhi -> h_buf[0:]
    const size_t OFF_XLO     = 91750400;   // 4,194,304: xlo -> h_buf[4MB:]
    const size_t OFF_ROPE    = 95944704;   // 2048*32*8 = 524,288

    __hip_bfloat16* wt_qkvg_hi = (__hip_bfloat16*)(ws + OFF_WT_QKVG);
    __hip_bfloat16* wt_qkvg_lo = (__hip_bfloat16*)(ws + OFF_R1);
    __hip_bfloat16* wt_o    = (__hip_bfloat16*)(ws + OFF_WT_O);
    __hip_bfloat16* wt_gu   = (__hip_bfloat16*)(ws + OFF_WT_GU);
    __hip_bfloat16* wt_down = (__hip_bfloat16*)(ws + OFF_WT_DOWN);
    float*          X1      = (float*)(ws + OFF_X1);
    __hip_bfloat16* GU      = (__hip_bfloat16*)(ws + OFF_X1);   // after X1 dead
    float*          o_buf   = (float*)(ws + OFF_R1);            // after qkv gemm
    __hip_bfloat16* mbf     = (__hip_bfloat16*)(ws + OFF_R1);   // after o/attn/ybf dead
    __hip_bfloat16* attn_bf = (__hip_bfloat16*)(ws + OFF_ATTN);
    __hip_bfloat16* xhi     = (__hip_bfloat16*)(ws + OFF_XHI);
    __hip_bfloat16* xlo     = (__hip_bfloat16*)(ws + OFF_XLO);
    float*          h_buf   = (float*)(ws + OFF_XHI);           // after qkv gemm
    __hip_bfloat16* ybf     = (__hip_bfloat16*)(ws + OFF_YBF);
    float2*         rope_cs = (float2*)(ws + OFF_ROPE);

    dim3 tb(32, 8);
    rope_table_kernel<<<256, 256, 0, stream>>>(rope_cs);
    rmsnorm_split_kernel<<<2048, 256, 0, stream>>>(hidden, norm1_w, xhi, xlo);
    // fused qkv/gate/g/b weight: split hi/lo transpose
    transpose_split_kernel<<<dim3(32, 32), tb, 0, stream>>>(q_w,    wt_qkvg_hi,               wt_qkvg_lo,               1024, 1024, 1024);
    transpose_split_kernel<<<dim3(32, 32), tb, 0, stream>>>(k_w,    wt_qkvg_hi + 1024 * 1024, wt_qkvg_lo + 1024 * 1024, 1024, 1024, 1024);
    transpose_split_kernel<<<dim3(32, 32), tb, 0, stream>>>(v_w,    wt_qkvg_hi + 2048 * 1024, wt_qkvg_lo + 2048 * 1024, 1024, 1024, 1024);
    transpose_split_kernel<<<dim3(32, 32), tb, 0, stream>>>(gate_w, wt_qkvg_hi + 3072 * 1024, wt_qkvg_lo + 3072 * 1024, 1024, 1024, 1024);
    transpose_split_kernel<<<dim3(32, 1),  tb, 0, stream>>>(g_w,    wt_qkvg_hi + 4096 * 1024, wt_qkvg_lo + 4096 * 1024, 1024, 16,   16);
    transpose_split_kernel<<<dim3(32, 4),  tb, 0, stream>>>(b_w,    wt_qkvg_hi + 4112 * 1024, wt_qkvg_lo + 4112 * 1024, 1024, 16,   112);
    // single-precision bf16 transposes for the rest
    transpose_bf16_kernel<<<dim3(32, 32),  tb, 0, stream>>>(o_w,        wt_o,               1024, 1024, 1024);
    transpose_bf16_kernel<<<dim3(32, 128), tb, 0, stream>>>(mlp_gate_w, wt_gu,              1024, 4096, 4096);
    transpose_bf16_kernel<<<dim3(32, 128), tb, 0, stream>>>(mlp_up_w,   wt_gu + 4096 * 1024, 1024, 4096, 4096);
    transpose_bf16_kernel<<<dim3(128, 32), tb, 0, stream>>>(mlp_down_w, wt_down,            4096, 1024, 1024);
    // fused q|k|v|gate|g|b projection (split precision -> ~f32 accurate)
    gemm_bt_split<<<dim3(33, 16), 256, 0, stream>>>(xhi, xlo, wt_qkvg_hi, wt_qkvg_lo, X1, 2048, NQKV, 1024);
    // rope + qk L2 norm (in place on X1)
    rope_kernel<<<8192, 256, 0, stream>>>(X1, rope_cs);
    // sequential delta-rule scan
    scan_kernel<<<16, 64, 0, stream>>>(X1, o_buf);
    // o_norm * silu(gate)
    o_gate_kernel<<<8192, 256, 0, stream>>>(o_buf, X1, o_norm_w, attn_bf);
    // attn out projection -> h (f32) ; h region overlays xhi/xlo (dead now)
    gemm_bt<false><<<dim3(8, 16), 256, 0, stream>>>(attn_bf, wt_o, h_buf, 2048, 1024, 1024);
    // h = hidden + attn; ybf = rmsnorm(h)
    add_rmsnorm_kernel<<<2048, 256, 0, stream>>>(hidden, h_buf, norm2_w, ybf);
    // mlp gate|up fused (writes GU over dead X1)
    gemm_bt<true><<<dim3(64, 16), 256, 0, stream>>>(ybf, wt_gu, GU, 2048, 8192, 1024);
    // m = silu(G)*U (mbf overlays o_buf/attn_bf/ybf, all dead)
    silu_mul_kernel<<<32768, 256, 0, stream>>>(GU, mbf);
    // down projection -> d_out
    gemm_bt<false><<<dim3(8, 16), 256, 0, stream>>>(mbf, wt_down, (float*)d_out, 2048, 1024, 4096);
    // out += h
    final_add_kernel<<<8192, 256, 0, stream>>>((float*)d_out, h_buf);
}

// Round 3
// 993.475 us; speedup vs baseline: 3.1234x; 3.1234x over previous
//
#include <hip/hip_runtime.h>
#include <hip/hip_bf16.h>

// ---------------------------------------------------------------------------
// DepthDeltaNetDecoderLayer: B=1, T=2048, D=1024, H=16, DK=DV=64, FF=4096
// Round 2: chunked WY-transform delta-rule scan (C=64): serial 2048-step scan
// (2754us, 0.2% occupancy) -> 3 parallel MFMA phases. Recurrence-critical
// matmuls use split-bf16 (hi+lo, 3 products) for ~f32 accuracy.
// ---------------------------------------------------------------------------

#define T_SEQ 2048
#define D_MODEL 1024
#define NH 16
#define DK 64
#define DV 64
#define FF 4096
#define NQKV 4224   // q(1024) k(1024) v(1024) gate(1024) g(16@4096) b(16@4112) pad->4224
#define LP 72       // padded LDS stride (shorts) for 64x64 bf16 operand tiles

typedef __bf16 bf16x8 __attribute__((ext_vector_type(8)));
typedef float  fx4    __attribute__((ext_vector_type(4)));

// ---------------------------------------------------------------- rope table
__global__ void rope_table_kernel(float2* __restrict__ cs) {
    int idx = blockIdx.x * 256 + threadIdx.x;      // t*32 + i, 65536 total
    int t = idx >> 5, i = idx & 31;
    float freq = (float)t * powf(10000.f, -(float)i / 32.f);
    cs[idx] = make_float2(cosf(freq), sinf(freq));
}

// --------------------------------------- row rmsnorm -> bf16 hi + bf16 lo
__global__ __launch_bounds__(256) void rmsnorm_split_kernel(
    const float* __restrict__ in, const float* __restrict__ w,
    __hip_bfloat16* __restrict__ hi, __hip_bfloat16* __restrict__ lo) {
    int t = blockIdx.x;
    int d = threadIdx.x * 4;
    const float4 v = *(const float4*)(in + (size_t)t * D_MODEL + d);
    float ss = v.x * v.x + v.y * v.y + v.z * v.z + v.w * v.w;
#pragma unroll
    for (int m = 32; m; m >>= 1) ss += __shfl_xor(ss, m, 64);
    __shared__ float wsum[4];
    if ((threadIdx.x & 63) == 0) wsum[threadIdx.x >> 6] = ss;
    __syncthreads();
    float tot = wsum[0] + wsum[1] + wsum[2] + wsum[3];
    float sc = rsqrtf(tot * (1.f / 1024.f) + 1e-6f);
    const float4 wv = *(const float4*)(w + d);
    float xs[4] = {v.x * sc * wv.x, v.y * sc * wv.y, v.z * sc * wv.z, v.w * sc * wv.w};
    __hip_bfloat16* hp = hi + (size_t)t * D_MODEL + d;
    __hip_bfloat16* lp = lo + (size_t)t * D_MODEL + d;
#pragma unroll
    for (int j = 0; j < 4; ++j) {
        __hip_bfloat16 h = __float2bfloat16(xs[j]);
        hp[j] = h;
        lp[j] = __float2bfloat16(xs[j] - __bfloat162float(h));
    }
}

// ------------------------------------------- W (KxN f32) -> Wt (Npad x K bf16)
__global__ void transpose_bf16_kernel(const float* __restrict__ W,
                                      __hip_bfloat16* __restrict__ Wt,
                                      int K, int N, int Npad) {
    __shared__ float tile[32][33];
    int k0 = blockIdx.x * 32, n0 = blockIdx.y * 32;
    int tx = threadIdx.x, ty = threadIdx.y;   // (32,8)
#pragma unroll
    for (int i = 0; i < 32; i += 8) {
        int n = n0 + tx;
        tile[ty + i][tx] = (n < N) ? W[(size_t)(k0 + ty + i) * N + n] : 0.f;
    }
    __syncthreads();
#pragma unroll
    for (int i = 0; i < 32; i += 8) {
        int n = n0 + ty + i;
        if (n < Npad) Wt[(size_t)n * K + k0 + tx] = __float2bfloat16(tile[tx][ty + i]);
    }
}

// ---------------------- W (KxN f32) -> Wt_hi, Wt_lo (Npad x K bf16 each)
__global__ void transpose_split_kernel(const float* __restrict__ W,
                                       __hip_bfloat16* __restrict__ Wt_hi,
                                       __hip_bfloat16* __restrict__ Wt_lo,
                                       int K, int N, int Npad) {
    __shared__ float tile[32][33];
    int k0 = blockIdx.x * 32, n0 = blockIdx.y * 32;
    int tx = threadIdx.x, ty = threadIdx.y;   // (32,8)
#pragma unroll
    for (int i = 0; i < 32; i += 8) {
        int n = n0 + tx;
        tile[ty + i][tx] = (n < N) ? W[(size_t)(k0 + ty + i) * N + n] : 0.f;
    }
    __syncthreads();
#pragma unroll
    for (int i = 0; i < 32; i += 8) {
        int n = n0 + ty + i;
        if (n < Npad) {
            float x = tile[tx][ty + i];
            __hip_bfloat16 h = __float2bfloat16(x);
            Wt_hi[(size_t)n * K + k0 + tx] = h;
            Wt_lo[(size_t)n * K + k0 + tx] = __float2bfloat16(x - __bfloat162float(h));
        }
    }
}

// ------------------------------------------------------------------- GEMM
// A: MxK bf16 row-major; Bt: NxK bf16 row-major (B transposed); C: MxN.
template <bool OUT_BF16>
__global__ __launch_bounds__(256) void gemm_bt(
    const __hip_bfloat16* __restrict__ A, const __hip_bfloat16* __restrict__ Bt,
    void* __restrict__ Cout, int M, int N, int K) {
    __shared__ short sA[128 * 32];
    __shared__ short sB[128 * 32];
    const int tid = threadIdx.x;
    const int w = tid >> 6, lane = tid & 63;
    const int bn0 = blockIdx.x * 128, bm0 = blockIdx.y * 128;
    const int wr = w >> 1, wc = w & 1;

    fx4 acc[4][4];
#pragma unroll
    for (int m = 0; m < 4; ++m)
#pragma unroll
        for (int n = 0; n < 4; ++n) acc[m][n] = {0.f, 0.f, 0.f, 0.f};

    for (int k0 = 0; k0 < K; k0 += 32) {
        __syncthreads();
#pragma unroll
        for (int i = 0; i < 2; ++i) {
            int c = i * 256 + tid;
            int r = c >> 2, kk = (c & 3) * 8;
            int4 va = *(const int4*)(A + (size_t)(bm0 + r) * K + k0 + kk);
            *(int4*)(sA + c * 8) = va;
            int4 vb = *(const int4*)(Bt + (size_t)(bn0 + r) * K + k0 + kk);
            *(int4*)(sB + c * 8) = vb;
        }
        __syncthreads();
        bf16x8 af[4], bfv[4];
#pragma unroll
        for (int m = 0; m < 4; ++m)
            af[m] = *(const bf16x8*)(sA + (wr * 64 + m * 16 + (lane & 15)) * 32 + (lane >> 4) * 8);
#pragma unroll
        for (int n = 0; n < 4; ++n)
            bfv[n] = *(const bf16x8*)(sB + (wc * 64 + n * 16 + (lane & 15)) * 32 + (lane >> 4) * 8);
#pragma unroll
        for (int m = 0; m < 4; ++m)
#pragma unroll
            for (int n = 0; n < 4; ++n)
                acc[m][n] = __builtin_amdgcn_mfma_f32_16x16x32_bf16(af[m], bfv[n], acc[m][n], 0, 0, 0);
    }
#pragma unroll
    for (int m = 0; m < 4; ++m) {
        int row = bm0 + wr * 64 + m * 16 + (lane >> 4) * 4;
#pragma unroll
        for (int n = 0; n < 4; ++n) {
            int col = bn0 + wc * 64 + n * 16 + (lane & 15);
#pragma unroll
            for (int j = 0; j < 4; ++j) {
                float val = acc[m][n][j];
                if (OUT_BF16)
                    ((__hip_bfloat16*)Cout)[(size_t)(row + j) * N + col] = __float2bfloat16(val);
                else
                    ((float*)Cout)[(size_t)(row + j) * N + col] = val;
            }
        }
    }
}

// ------------------------------------- split-precision GEMM (3 bf16 products)
__global__ __launch_bounds__(256) void gemm_bt_split(
    const __hip_bfloat16* __restrict__ Ah, const __hip_bfloat16* __restrict__ Al,
    const __hip_bfloat16* __restrict__ Bth, const __hip_bfloat16* __restrict__ Btl,
    float* __restrict__ Cout, int M, int N, int K) {
    __shared__ short sAh[128 * 32];
    __shared__ short sAl[128 * 32];
    __shared__ short sBh[128 * 32];
    __shared__ short sBl[128 * 32];
    const int tid = threadIdx.x;
    const int w = tid >> 6, lane = tid & 63;
    const int bn0 = blockIdx.x * 128, bm0 = blockIdx.y * 128;
    const int wr = w >> 1, wc = w & 1;

    fx4 acc[4][4];
#pragma unroll
    for (int m = 0; m < 4; ++m)
#pragma unroll
        for (int n = 0; n < 4; ++n) acc[m][n] = {0.f, 0.f, 0.f, 0.f};

    for (int k0 = 0; k0 < K; k0 += 32) {
        __syncthreads();
#pragma unroll
        for (int i = 0; i < 2; ++i) {
            int c = i * 256 + tid;
            int r = c >> 2, kk = (c & 3) * 8;
            size_t ga = (size_t)(bm0 + r) * K + k0 + kk;
            size_t gb = (size_t)(bn0 + r) * K + k0 + kk;
            *(int4*)(sAh + c * 8) = *(const int4*)(Ah + ga);
            *(int4*)(sAl + c * 8) = *(const int4*)(Al + ga);
            *(int4*)(sBh + c * 8) = *(const int4*)(Bth + gb);
            *(int4*)(sBl + c * 8) = *(const int4*)(Btl + gb);
        }
        __syncthreads();
        bf16x8 ah[4], al[4], bh[4], bl[4];
#pragma unroll
        for (int m = 0; m < 4; ++m) {
            int off = (wr * 64 + m * 16 + (lane & 15)) * 32 + (lane >> 4) * 8;
            ah[m] = *(const bf16x8*)(sAh + off);
            al[m] = *(const bf16x8*)(sAl + off);
        }
#pragma unroll
        for (int n = 0; n < 4; ++n) {
            int off = (wc * 64 + n * 16 + (lane & 15)) * 32 + (lane >> 4) * 8;
            bh[n] = *(const bf16x8*)(sBh + off);
            bl[n] = *(const bf16x8*)(sBl + off);
        }
#pragma unroll
        for (int m = 0; m < 4; ++m)
#pragma unroll
            for (int n = 0; n < 4; ++n) {
                acc[m][n] = __builtin_amdgcn_mfma_f32_16x16x32_bf16(ah[m], bh[n], acc[m][n], 0, 0, 0);
                acc[m][n] = __builtin_amdgcn_mfma_f32_16x16x32_bf16(ah[m], bl[n], acc[m][n], 0, 0, 0);
                acc[m][n] = __builtin_amdgcn_mfma_f32_16x16x32_bf16(al[m], bh[n], acc[m][n], 0, 0, 0);
            }
    }
#pragma unroll
    for (int m = 0; m < 4; ++m) {
        int row = bm0 + wr * 64 + m * 16 + (lane >> 4) * 4;
#pragma unroll
        for (int n = 0; n < 4; ++n) {
            int col = bn0 + wc * 64 + n * 16 + (lane & 15);
#pragma unroll
            for (int j = 0; j < 4; ++j)
                Cout[(size_t)(row + j) * N + col] = acc[m][n][j];
        }
    }
}

// --------------------------------------------- RoPE + L2-normalize q,k in place
__global__ __launch_bounds__(256) void rope_kernel(float* __restrict__ X1,
                                                   const float2* __restrict__ cs) {
    int w = threadIdx.x >> 6, lane = threadIdx.x & 63;
    int p = blockIdx.x * 4 + w;            // (t,h) pair, 32768 total
    int t = p >> 4, h = p & 15;
    float2 c = cs[t * 32 + (lane & 31)];
#pragma unroll
    for (int which = 0; which < 2; ++which) {
        float* base = X1 + (size_t)t * NQKV + which * 1024 + h * 64;
        float x = base[lane];
        float xo = __shfl(x, lane ^ 32, 64);
        float r = (lane < 32) ? -xo : xo;
        float y = x * c.x + r * c.y;
        float ss = y * y;
#pragma unroll
        for (int m = 32; m; m >>= 1) ss += __shfl_xor(ss, m, 64);
        base[lane] = y * rsqrtf(ss + 1e-12f);
    }
}

// ===================== chunked delta-rule: shared helpers =====================
// One wave computes rows [w*16,w*16+16) x 64 cols of C = A*Bt^T (K=64),
// split-bf16 3-product. Operands in LDS, padded stride LP.
__device__ __forceinline__ void mm64_3p(const short* Ah, const short* Al,
                                        const short* Bh, const short* Bl,
                                        int w, int lane, fx4 acc[4]) {
#pragma unroll
    for (int k0 = 0; k0 < 64; k0 += 32) {
        int ao = (w * 16 + (lane & 15)) * LP + k0 + ((lane >> 4) * 8);
        bf16x8 ah = *(const bf16x8*)(Ah + ao);
        bf16x8 al = *(const bf16x8*)(Al + ao);
#pragma unroll
        for (int n = 0; n < 4; ++n) {
            int bo = (n * 16 + (lane & 15)) * LP + k0 + ((lane >> 4) * 8);
            bf16x8 bh = *(const bf16x8*)(Bh + bo);
            bf16x8 bl = *(const bf16x8*)(Bl + bo);
            acc[n] = __builtin_amdgcn_mfma_f32_16x16x32_bf16(ah, bh, acc[n], 0, 0, 0);
            acc[n] = __builtin_amdgcn_mfma_f32_16x16x32_bf16(ah, bl, acc[n], 0, 0, 0);
            acc[n] = __builtin_amdgcn_mfma_f32_16x16x32_bf16(al, bh, acc[n], 0, 0, 0);
        }
    }
}

__device__ __forceinline__ void split_write(short* h, short* l, int off, float x) {
    __hip_bfloat16 hb = __float2bfloat16(x);
    ((__hip_bfloat16*)h)[off] = hb;
    ((__hip_bfloat16*)l)[off] = __float2bfloat16(x - __bfloat162float(hb));
}

// ---------------------------------------------------------- phase A (parallel)
// Per (head h, chunk c): WY transform. Writes (in place over X1):
//   q-region <- Qeff = diag(gprev)Q - Ptilde*W     (f32)
//   k-region <- Olocal = Ptilde*Uv                 (f32)
// and to scratch: Ac (bf16 hi/lo), BcT (f32).
__global__ __launch_bounds__(256) void phaseA_kernel(float* __restrict__ X1,
                                                     short* __restrict__ AcBuf,
                                                     float* __restrict__ BcBuf) {
    const int h = blockIdx.x & 15, c = blockIdx.x >> 4;
    const int tid = threadIdx.x, w = tid >> 6, lane = tid & 63;
    const int t0 = c * 64;

    __shared__ float sK[4096];
    __shared__ float sM[4096];
    __shared__ short b1h[64 * LP], b1l[64 * LP];   // K, later KhatT
    __shared__ short b2h[64 * LP], b2l[64 * LP];   // Q, later Ptilde
    __shared__ short b3h[64 * LP], b3l[64 * LP];   // UvT
    __shared__ short b4h[64 * LP], b4l[64 * LP];   // WT
    __shared__ float sLa[64], sB[64], sL[65], sGp[64], sRc[64];

    const float* q_g = X1 + (size_t)t0 * NQKV + h * 64;
    const float* k_g = q_g + 1024;
    const float* v_g = q_g + 2048;

    // per-step scalars: la = log(sigmoid(ga)) = -softplus(-ga); b = sigmoid(gb)
    if (tid < 64) {
        float ga = X1[(size_t)(t0 + tid) * NQKV + 4096 + h];
        float gb = X1[(size_t)(t0 + tid) * NQKV + 4112 + h];
        float z = -ga;
        sLa[tid] = -(fmaxf(z, 0.f) + log1pf(expf(-fabsf(z))));
        sB[tid] = 1.f / (1.f + expf(-gb));
    }
    __syncthreads();
    if (tid == 0) {
        float a = 0.f; sL[0] = 0.f;
        for (int t = 0; t < 64; ++t) { a += sLa[t]; sL[t + 1] = a; }
    }
    __syncthreads();
    if (tid < 64) {
        sGp[tid] = expf(sL[tid]);               // gamma_{t-1}
        sRc[tid] = expf(sL[64] - sL[tid + 1]);  // gammaEnd / gamma_s
    }
    // stage K (f32)
    for (int idx = tid; idx < 4096; idx += 256) {
        int r = idx >> 6, cc = idx & 63;
        sK[idx] = k_g[(size_t)r * NQKV + cc];
    }
    __syncthreads();
    // K -> buf1 (hi/lo)
    for (int idx = tid; idx < 4096; idx += 256)
        split_write(b1h, b1l, (idx >> 6) * LP + (idx & 63), sK[idx]);
    __syncthreads();

    // G = K K^T -> M (strictly lower, scaled)
    {
        fx4 acc[4];
#pragma unroll
        for (int n = 0; n < 4; ++n) acc[n] = {0.f, 0.f, 0.f, 0.f};
        mm64_3p(b1h, b1l, b1h, b1l, w, lane, acc);
#pragma unroll
        for (int n = 0; n < 4; ++n)
#pragma unroll
            for (int jj = 0; jj < 4; ++jj) {
                int t = w * 16 + (lane >> 4) * 4 + jj, s = n * 16 + (lane & 15);
                sM[t * 64 + s] = (s < t) ? sB[t] * expf(sL[t] - sL[s + 1]) * acc[n][jj] : 0.f;
            }
    }
    __syncthreads();

    // waves 0-1: forward-solve (I+M)X = [diag(b)V | diag(b*gprev)K] -> UvT,WT
    // waves 2-3: convert Q -> buf2
    if (w < 2) {
        const int j = tid;   // 0..127 (column of X)
        float x[64];
#pragma unroll
        for (int t = 0; t < 64; ++t) {
            float rhs = (j < 64) ? sB[t] * v_g[(size_t)t * NQKV + j]
                                 : sB[t] * sGp[t] * sK[t * 64 + (j - 64)];
#pragma unroll
            for (int s = 0; s < t; ++s) rhs = fmaf(-sM[t * 64 + s], x[s], rhs);
            x[t] = rhs;
        }
        short* oh = (j < 64) ? b3h : b4h;
        short* ol = (j < 64) ? b3l : b4l;
        int r = j & 63;
#pragma unroll
        for (int t = 0; t < 64; ++t) split_write(oh, ol, r * LP + t, x[t]);
    } else {
        for (int idx = tid - 128; idx < 4096; idx += 128) {
            int r = idx >> 6, cc = idx & 63;
            split_write(b2h, b2l, r * LP + cc, q_g[(size_t)r * NQKV + cc]);
        }
    }
    __syncthreads();

    // P = Q K^T
    fx4 pacc[4];
#pragma unroll
    for (int n = 0; n < 4; ++n) pacc[n] = {0.f, 0.f, 0.f, 0.f};
    mm64_3p(b2h, b2l, b1h, b1l, w, lane, pacc);
    __syncthreads();   // all reads of buf1/buf2 complete before overwrite
    // Ptilde -> buf2 (masked, scaled)
#pragma unroll
    for (int n = 0; n < 4; ++n)
#pragma unroll
        for (int jj = 0; jj < 4; ++jj) {
            int t = w * 16 + (lane >> 4) * 4 + jj, s = n * 16 + (lane & 15);
            float pv = (s < t) ? expf(sL[t] - sL[s + 1]) * pacc[n][jj] : 0.f;
            split_write(b2h, b2l, t * LP + s, pv);
        }
    // KhatT -> buf1:  [i][s] = rC[s] * K[s][i]
    for (int idx = tid; idx < 4096; idx += 256) {
        int s = idx >> 6, i = idx & 63;
        split_write(b1h, b1l, i * LP + s, sRc[s] * sK[s * 64 + i]);
    }
    __syncthreads();

    // Olocal = Ptilde @ Uv  -> overwrite k-region (f32)
    {
        fx4 acc[4];
#pragma unroll
        for (int n = 0; n < 4; ++n) acc[n] = {0.f, 0.f, 0.f, 0.f};
        mm64_3p(b2h, b2l, b3h, b3l, w, lane, acc);
        float* og = X1 + (size_t)t0 * NQKV + 1024 + h * 64;
#pragma unroll
        for (int n = 0; n < 4; ++n)
#pragma unroll
            for (int jj = 0; jj < 4; ++jj) {
                int t = w * 16 + (lane >> 4) * 4 + jj, s = n * 16 + (lane & 15);
                og[(size_t)t * NQKV + s] = acc[n][jj];
            }
    }
    // PW = Ptilde @ W ; Qeff = diag(gprev)Q - PW -> overwrite q-region (f32)
    {
        fx4 acc[4];
#pragma unroll
        for (int n = 0; n < 4; ++n) acc[n] = {0.f, 0.f, 0.f, 0.f};
        mm64_3p(b2h, b2l, b4h, b4l, w, lane, acc);
        float* qg = X1 + (size_t)t0 * NQKV + h * 64;
#pragma unroll
        for (int n = 0; n < 4; ++n)
#pragma unroll
            for (int jj = 0; jj < 4; ++jj) {
                int t = w * 16 + (lane >> 4) * 4 + jj, s = n * 16 + (lane & 15);
                float qv = qg[(size_t)t * NQKV + s];
                qg[(size_t)t * NQKV + s] = sGp[t] * qv - acc[n][jj];
            }
    }
    // Ac = gammaEnd*I - KhatT @ W  -> AcBuf (bf16 hi/lo, row-major [i][j])
    {
        fx4 acc[4];
#pragma unroll
        for (int n = 0; n < 4; ++n) acc[n] = {0.f, 0.f, 0.f, 0.f};
        mm64_3p(b1h, b1l, b4h, b4l, w, lane, acc);
        float gend = expf(sL[64]);
        size_t abase = (size_t)(h * 32 + c) * 8192;
#pragma unroll
        for (int n = 0; n < 4; ++n)
#pragma unroll
            for (int jj = 0; jj < 4; ++jj) {
                int i = w * 16 + (lane >> 4) * 4 + jj, jd = n * 16 + (lane & 15);
                float av = ((i == jd) ? gend : 0.f) - acc[n][jj];
                __hip_bfloat16 hb = __float2bfloat16(av);
                ((__hip_bfloat16*)AcBuf)[abase + i * 64 + jd] = hb;
                ((__hip_bfloat16*)AcBuf)[abase + 4096 + i * 64 + jd] =
                    __float2bfloat16(av - __bfloat162float(hb));
            }
    }
    // BcT = (KhatT @ Uv)^T = UvT @ KhatT' -> BcBuf (f32, [v][i])
    {
        fx4 acc[4];
#pragma unroll
        for (int n = 0; n < 4; ++n) acc[n] = {0.f, 0.f, 0.f, 0.f};
        mm64_3p(b3h, b3l, b1h, b1l, w, lane, acc);
        size_t bbase = (size_t)(h * 32 + c) * 4096;
#pragma unroll
        for (int n = 0; n < 4; ++n)
#pragma unroll
            for (int jj = 0; jj < 4; ++jj) {
                int jv = w * 16 + (lane >> 4) * 4 + jj, i = n * 16 + (lane & 15);
                BcBuf[bbase + jv * 64 + i] = acc[n][jj];
            }
    }
}

// --------------------------------------------------- phase B (state recurrence)
// Per head: S'^T = S^T @ Ac' + Bc^T over 32 chunks; stores state entering each
// chunk (f32) into X1's dead v-region.
__global__ __launch_bounds__(256) void phaseB_kernel(const short* __restrict__ AcBuf,
                                                     const float* __restrict__ BcBuf,
                                                     float* __restrict__ X1) {
    const int h = blockIdx.x;
    const int tid = threadIdx.x, w = tid >> 6, lane = tid & 63;
    __shared__ float sST[4096];
    __shared__ short sSh[64 * LP], sSl[64 * LP];
    __shared__ short sAh[64 * LP], sAl[64 * LP];
    for (int idx = tid; idx < 4096; idx += 256) sST[idx] = 0.f;
    __syncthreads();
    for (int c = 0; c < 32; ++c) {
        float* stg = X1 + (size_t)(c * 64) * NQKV + 2048 + h * 64;
        for (int idx = tid; idx < 4096; idx += 256) {
            int r = idx >> 6, i = idx & 63;
            float xv = sST[idx];
            stg[(size_t)r * NQKV + i] = xv;            // state entering chunk c
            split_write(sSh, sSl, r * LP + i, xv);
        }
        const __hip_bfloat16* ag = (const __hip_bfloat16*)AcBuf + (size_t)(h * 32 + c) * 8192;
        for (int idx = tid; idx < 4096; idx += 256) {
            int r = idx >> 6, i = idx & 63;
            ((__hip_bfloat16*)sAh)[r * LP + i] = ag[idx];
            ((__hip_bfloat16*)sAl)[r * LP + i] = ag[4096 + idx];
        }
        __syncthreads();
        fx4 acc[4];
        const float* bg = BcBuf + (size_t)(h * 32 + c) * 4096;
#pragma unroll
        for (int n = 0; n < 4; ++n)
#pragma unroll
            for (int jj = 0; jj < 4; ++jj)
                acc[n][jj] = bg[(w * 16 + (lane >> 4) * 4 + jj) * 64 + n * 16 + (lane & 15)];
        mm64_3p(sSh, sSl, sAh, sAl, w, lane, acc);
#pragma unroll
        for (int n = 0; n < 4; ++n)
#pragma unroll
            for (int jj = 0; jj < 4; ++jj)
                sST[(w * 16 + (lane >> 4) * 4 + jj) * 64 + n * 16 + (lane & 15)] = acc[n][jj];
        __syncthreads();
    }
}

// --------------------------------------------- phase C (outputs + epilogue)
// o = Qeff @ S_c + Olocal; then rmsnorm(o)*o_norm_w*silu(gate) -> attn_bf.
__global__ __launch_bounds__(256) void phaseC_kernel(const float* __restrict__ X1,
                                                     const float* __restrict__ onw,
                                                     __hip_bfloat16* __restrict__ attn_bf) {
    const int h = blockIdx.x & 15, c = blockIdx.x >> 4;
    const int tid = threadIdx.x, w = tid >> 6, lane = tid & 63;
    const int t0 = c * 64;
    __shared__ short qh[64 * LP], ql[64 * LP];
    __shared__ short sh_[64 * LP], sl_[64 * LP];
    __shared__ float sO[4096];
    __shared__ float part[64][4];
    const float* qe = X1 + (size_t)t0 * NQKV + h * 64;          // Qeff
    const float* stg = X1 + (size_t)t0 * NQKV + 2048 + h * 64;  // S^T (entering c)
    const float* ol = X1 + (size_t)t0 * NQKV + 1024 + h * 64;   // Olocal
    for (int idx = tid; idx < 4096; idx += 256) {
        int r = idx >> 6, i = idx & 63;
        split_write(qh, ql, r * LP + i, qe[(size_t)r * NQKV + i]);
        split_write(sh_, sl_, r * LP + i, stg[(size_t)r * NQKV + i]);
    }
    __syncthreads();
    fx4 acc[4];
#pragma unroll
    for (int n = 0; n < 4; ++n)
#pragma unroll
        for (int jj = 0; jj < 4; ++jj)
            acc[n][jj] = ol[(size_t)(w * 16 + (lane >> 4) * 4 + jj) * NQKV + n * 16 + (lane & 15)];
    mm64_3p(qh, ql, sh_, sl_, w, lane, acc);
#pragma unroll
    for (int n = 0; n < 4; ++n)
#pragma unroll
        for (int jj = 0; jj < 4; ++jj)
            sO[(w * 16 + (lane >> 4) * 4 + jj) * 64 + n * 16 + (lane & 15)] = acc[n][jj];
    __syncthreads();
    int r = tid >> 2, qq = tid & 3;
    float ss = 0.f;
#pragma unroll
    for (int i2 = 0; i2 < 16; ++i2) { float v = sO[r * 64 + qq * 16 + i2]; ss += v * v; }
    part[r][qq] = ss;
    __syncthreads();
    float tot = part[r][0] + part[r][1] + part[r][2] + part[r][3];
    float sc = rsqrtf(tot * (1.f / 64.f) + 1e-6f);
    const float* gg = X1 + (size_t)(t0 + r) * NQKV + 3072 + h * 64;
#pragma unroll
    for (int i2 = 0; i2 < 16; ++i2) {
        int j = qq * 16 + i2;
        float on = sO[r * 64 + j] * sc * onw[j];
        float g = gg[j];
        float sg = g / (1.f + expf(-g));
        attn_bf[(size_t)(t0 + r) * 1024 + h * 64 + j] = __float2bfloat16(on * sg);
    }
}

// ---------------------------- h = hidden + attn (in place); ybf = rmsnorm(h)
__global__ __launch_bounds__(256) void add_rmsnorm_kernel(
    const float* __restrict__ hidden, float* __restrict__ acc,
    const float* __restrict__ w, __hip_bfloat16* __restrict__ out) {
    int t = blockIdx.x;
    int d = threadIdx.x * 4;
    float4 a = *(const float4*)(acc + (size_t)t * D_MODEL + d);
    float4 hd = *(const float4*)(hidden + (size_t)t * D_MODEL + d);
    float4 h4 = make_float4(a.x + hd.x, a.y + hd.y, a.z + hd.z, a.w + hd.w);
    *(float4*)(acc + (size_t)t * D_MODEL + d) = h4;
    float ss = h4.x * h4.x + h4.y * h4.y + h4.z * h4.z + h4.w * h4.w;
#pragma unroll
    for (int m = 32; m; m >>= 1) ss += __shfl_xor(ss, m, 64);
    __shared__ float wsum[4];
    if ((threadIdx.x & 63) == 0) wsum[threadIdx.x >> 6] = ss;
    __syncthreads();
    float tot = wsum[0] + wsum[1] + wsum[2] + wsum[3];
    float sc = rsqrtf(tot * (1.f / 1024.f) + 1e-6f);
    const float4 wv = *(const float4*)(w + d);
    __hip_bfloat16* op = out + (size_t)t * D_MODEL + d;
    op[0] = __float2bfloat16(h4.x * sc * wv.x);
    op[1] = __float2bfloat16(h4.y * sc * wv.y);
    op[2] = __float2bfloat16(h4.z * sc * wv.z);
    op[3] = __float2bfloat16(h4.w * sc * wv.w);
}

// ---------------------------------------------- m = silu(G) * U (bf16 in/out)
__global__ __launch_bounds__(256) void silu_mul_kernel(const __hip_bfloat16* __restrict__ GU,
                                                       __hip_bfloat16* __restrict__ m) {
    size_t i = (size_t)blockIdx.x * 256 + threadIdx.x;   // 2048*4096
    size_t t = i >> 12, j = i & 4095;
    float g = __bfloat162float(GU[t * 8192 + j]);
    float u = __bfloat162float(GU[t * 8192 + 4096 + j]);
    m[i] = __float2bfloat16(u * g / (1.f + expf(-g)));
}

// ----------------------------------------------------------- out += h
__global__ __launch_bounds__(256) void final_add_kernel(float* __restrict__ out,
                                                        const float* __restrict__ h) {
    size_t i = (size_t)blockIdx.x * 256 + threadIdx.x;
    out[i] += h[i];
}

// ---------------------------------------------------------------------------
extern "C" void kernel_launch(void* const* d_in, const int* in_sizes, int n_in,
                              void* d_out, int out_size, void* d_ws, size_t ws_size,
                              hipStream_t stream) {
    (void)in_sizes; (void)n_in; (void)out_size; (void)ws_size;
    const float* hidden     = (const float*)d_in[0];
    const float* norm1_w    = (const float*)d_in[1];
    const float* q_w        = (const float*)d_in[2];
    const float* k_w        = (const float*)d_in[3];
    const float* v_w        = (const float*)d_in[4];
    const float* g_w        = (const float*)d_in[5];
    const float* b_w        = (const float*)d_in[6];
    const float* gate_w     = (const float*)d_in[7];
    const float* o_norm_w   = (const float*)d_in[8];
    const float* o_w        = (const float*)d_in[9];
    const float* norm2_w    = (const float*)d_in[10];
    const float* mlp_gate_w = (const float*)d_in[11];
    const float* mlp_up_w   = (const float*)d_in[12];
    const float* mlp_down_w = (const float*)d_in[13];

    char* ws = (char*)d_ws;
    // workspace (~92 MiB), timeline-reused:
    const size_t OFF_WT_QKVG = 0;          // wt_qkvg_hi -> AcBuf (phase A/B)
    const size_t OFF_WT_O    = 8650752;
    const size_t OFF_WT_GU   = 10747904;
    const size_t OFF_WT_DOWN = 27525120;
    const size_t OFF_X1      = 35913728;   // X1 f32 (q->Qeff, k->Olocal, v->S states) -> GU bf16
    const size_t OFF_R1      = 70516736;   // wt_qkvg_lo -> BcBuf -> mbf
    const size_t OFF_ATTN    = 79167488;
    const size_t OFF_YBF     = 83361792;
    const size_t OFF_XHI     = 87556096;   // xhi/xlo -> h_buf
    const size_t OFF_XLO     = 91750400;
    const size_t OFF_ROPE    = 95944704;

    __hip_bfloat16* wt_qkvg_hi = (__hip_bfloat16*)(ws + OFF_WT_QKVG);
    __hip_bfloat16* wt_qkvg_lo = (__hip_bfloat16*)(ws + OFF_R1);
    __hip_bfloat16* wt_o    = (__hip_bfloat16*)(ws + OFF_WT_O);
    __hip_bfloat16* wt_gu   = (__hip_bfloat16*)(ws + OFF_WT_GU);
    __hip_bfloat16* wt_down = (__hip_bfloat16*)(ws + OFF_WT_DOWN);
    float*          X1      = (float*)(ws + OFF_X1);
    __hip_bfloat16* GU      = (__hip_bfloat16*)(ws + OFF_X1);
    short*          AcBuf   = (short*)(ws + OFF_WT_QKVG);       // after qkv gemm
    float*          BcBuf   = (float*)(ws + OFF_R1);            // after qkv gemm
    __hip_bfloat16* mbf     = (__hip_bfloat16*)(ws + OFF_R1);   // after phase B/C
    __hip_bfloat16* attn_bf = (__hip_bfloat16*)(ws + OFF_ATTN);
    __hip_bfloat16* xhi     = (__hip_bfloat16*)(ws + OFF_XHI);
    __hip_bfloat16* xlo     = (__hip_bfloat16*)(ws + OFF_XLO);
    float*          h_buf   = (float*)(ws + OFF_XHI);
    __hip_bfloat16* ybf     = (__hip_bfloat16*)(ws + OFF_YBF);
    float2*         rope_cs = (float2*)(ws + OFF_ROPE);

    dim3 tb(32, 8);
    rope_table_kernel<<<256, 256, 0, stream>>>(rope_cs);
    rmsnorm_split_kernel<<<2048, 256, 0, stream>>>(hidden, norm1_w, xhi, xlo);
    transpose_split_kernel<<<dim3(32, 32), tb, 0, stream>>>(q_w,    wt_qkvg_hi,               wt_qkvg_lo,               1024, 1024, 1024);
    transpose_split_kernel<<<dim3(32, 32), tb, 0, stream>>>(k_w,    wt_qkvg_hi + 1024 * 1024, wt_qkvg_lo + 1024 * 1024, 1024, 1024, 1024);
    transpose_split_kernel<<<dim3(32, 32), tb, 0, stream>>>(v_w,    wt_qkvg_hi + 2048 * 1024, wt_qkvg_lo + 2048 * 1024, 1024, 1024, 1024);
    transpose_split_kernel<<<dim3(32, 32), tb, 0, stream>>>(gate_w, wt_qkvg_hi + 3072 * 1024, wt_qkvg_lo + 3072 * 1024, 1024, 1024, 1024);
    transpose_split_kernel<<<dim3(32, 1),  tb, 0, stream>>>(g_w,    wt_qkvg_hi + 4096 * 1024, wt_qkvg_lo + 4096 * 1024, 1024, 16,   16);
    transpose_split_kernel<<<dim3(32, 4),  tb, 0, stream>>>(b_w,    wt_qkvg_hi + 4112 * 1024, wt_qkvg_lo + 4112 * 1024, 1024, 16,   112);
    transpose_bf16_kernel<<<dim3(32, 32),  tb, 0, stream>>>(o_w,        wt_o,                1024, 1024, 1024);
    transpose_bf16_kernel<<<dim3(32, 128), tb, 0, stream>>>(mlp_gate_w, wt_gu,               1024, 4096, 4096);
    transpose_bf16_kernel<<<dim3(32, 128), tb, 0, stream>>>(mlp_up_w,   wt_gu + 4096 * 1024, 1024, 4096, 4096);
    transpose_bf16_kernel<<<dim3(128, 32), tb, 0, stream>>>(mlp_down_w, wt_down,             4096, 1024, 1024);
    // fused q|k|v|gate|g|b projection (split precision)
    gemm_bt_split<<<dim3(33, 16), 256, 0, stream>>>(xhi, xlo, wt_qkvg_hi, wt_qkvg_lo, X1, 2048, NQKV, 1024);
    rope_kernel<<<8192, 256, 0, stream>>>(X1, rope_cs);
    // chunked delta-rule scan
    phaseA_kernel<<<512, 256, 0, stream>>>(X1, AcBuf, BcBuf);
    phaseB_kernel<<<16, 256, 0, stream>>>(AcBuf, BcBuf, X1);
    phaseC_kernel<<<512, 256, 0, stream>>>(X1, o_norm_w, attn_bf);
    // attn out projection -> h
    gemm_bt<false><<<dim3(8, 16), 256, 0, stream>>>(attn_bf, wt_o, h_buf, 2048, 1024, 1024);
    add_rmsnorm_kernel<<<2048, 256, 0, stream>>>(hidden, h_buf, norm2_w, ybf);
    gemm_bt<true><<<dim3(64, 16), 256, 0, stream>>>(ybf, wt_gu, GU, 2048, 8192, 1024);
    silu_mul_kernel<<<32768, 256, 0, stream>>>(GU, mbf);
    gemm_bt<false><<<dim3(8, 16), 256, 0, stream>>>(mbf, wt_down, (float*)d_out, 2048, 1024, 4096);
    final_add_kernel<<<8192, 256, 0, stream>>>((float*)d_out, h_buf);
}

// Round 4
// 589.217 us; speedup vs baseline: 5.2664x; 1.6861x over previous
//
#include <hip/hip_runtime.h>
#include <hip/hip_bf16.h>

// ---------------------------------------------------------------------------
// DepthDeltaNetDecoderLayer: B=1, T=2048, D=1024, H=16, DK=DV=64, FF=4096
// Round 3: phaseA spill fix — triangular solve state moved from per-thread
// float x[64] (VGPR=256 cap -> ~580MB scratch traffic) into column-private
// LDS X[64][128]. Same op order (numerically identical), no barriers in the
// solve. Rider: wave-parallel prefix scan for the log-gamma cumsum.
// ---------------------------------------------------------------------------

#define T_SEQ 2048
#define D_MODEL 1024
#define NH 16
#define DK 64
#define DV 64
#define FF 4096
#define NQKV 4224   // q(1024) k(1024) v(1024) gate(1024) g(16@4096) b(16@4112) pad->4224
#define LP 72       // padded LDS stride (shorts) for 64x64 bf16 operand tiles

typedef __bf16 bf16x8 __attribute__((ext_vector_type(8)));
typedef float  fx4    __attribute__((ext_vector_type(4)));

// ---------------------------------------------------------------- rope table
__global__ void rope_table_kernel(float2* __restrict__ cs) {
    int idx = blockIdx.x * 256 + threadIdx.x;      // t*32 + i, 65536 total
    int t = idx >> 5, i = idx & 31;
    float freq = (float)t * powf(10000.f, -(float)i / 32.f);
    cs[idx] = make_float2(cosf(freq), sinf(freq));
}

// --------------------------------------- row rmsnorm -> bf16 hi + bf16 lo
__global__ __launch_bounds__(256) void rmsnorm_split_kernel(
    const float* __restrict__ in, const float* __restrict__ w,
    __hip_bfloat16* __restrict__ hi, __hip_bfloat16* __restrict__ lo) {
    int t = blockIdx.x;
    int d = threadIdx.x * 4;
    const float4 v = *(const float4*)(in + (size_t)t * D_MODEL + d);
    float ss = v.x * v.x + v.y * v.y + v.z * v.z + v.w * v.w;
#pragma unroll
    for (int m = 32; m; m >>= 1) ss += __shfl_xor(ss, m, 64);
    __shared__ float wsum[4];
    if ((threadIdx.x & 63) == 0) wsum[threadIdx.x >> 6] = ss;
    __syncthreads();
    float tot = wsum[0] + wsum[1] + wsum[2] + wsum[3];
    float sc = rsqrtf(tot * (1.f / 1024.f) + 1e-6f);
    const float4 wv = *(const float4*)(w + d);
    float xs[4] = {v.x * sc * wv.x, v.y * sc * wv.y, v.z * sc * wv.z, v.w * sc * wv.w};
    __hip_bfloat16* hp = hi + (size_t)t * D_MODEL + d;
    __hip_bfloat16* lp = lo + (size_t)t * D_MODEL + d;
#pragma unroll
    for (int j = 0; j < 4; ++j) {
        __hip_bfloat16 h = __float2bfloat16(xs[j]);
        hp[j] = h;
        lp[j] = __float2bfloat16(xs[j] - __bfloat162float(h));
    }
}

// ------------------------------------------- W (KxN f32) -> Wt (Npad x K bf16)
__global__ void transpose_bf16_kernel(const float* __restrict__ W,
                                      __hip_bfloat16* __restrict__ Wt,
                                      int K, int N, int Npad) {
    __shared__ float tile[32][33];
    int k0 = blockIdx.x * 32, n0 = blockIdx.y * 32;
    int tx = threadIdx.x, ty = threadIdx.y;   // (32,8)
#pragma unroll
    for (int i = 0; i < 32; i += 8) {
        int n = n0 + tx;
        tile[ty + i][tx] = (n < N) ? W[(size_t)(k0 + ty + i) * N + n] : 0.f;
    }
    __syncthreads();
#pragma unroll
    for (int i = 0; i < 32; i += 8) {
        int n = n0 + ty + i;
        if (n < Npad) Wt[(size_t)n * K + k0 + tx] = __float2bfloat16(tile[tx][ty + i]);
    }
}

// ---------------------- W (KxN f32) -> Wt_hi, Wt_lo (Npad x K bf16 each)
__global__ void transpose_split_kernel(const float* __restrict__ W,
                                       __hip_bfloat16* __restrict__ Wt_hi,
                                       __hip_bfloat16* __restrict__ Wt_lo,
                                       int K, int N, int Npad) {
    __shared__ float tile[32][33];
    int k0 = blockIdx.x * 32, n0 = blockIdx.y * 32;
    int tx = threadIdx.x, ty = threadIdx.y;   // (32,8)
#pragma unroll
    for (int i = 0; i < 32; i += 8) {
        int n = n0 + tx;
        tile[ty + i][tx] = (n < N) ? W[(size_t)(k0 + ty + i) * N + n] : 0.f;
    }
    __syncthreads();
#pragma unroll
    for (int i = 0; i < 32; i += 8) {
        int n = n0 + ty + i;
        if (n < Npad) {
            float x = tile[tx][ty + i];
            __hip_bfloat16 h = __float2bfloat16(x);
            Wt_hi[(size_t)n * K + k0 + tx] = h;
            Wt_lo[(size_t)n * K + k0 + tx] = __float2bfloat16(x - __bfloat162float(h));
        }
    }
}

// ------------------------------------------------------------------- GEMM
// A: MxK bf16 row-major; Bt: NxK bf16 row-major (B transposed); C: MxN.
template <bool OUT_BF16>
__global__ __launch_bounds__(256) void gemm_bt(
    const __hip_bfloat16* __restrict__ A, const __hip_bfloat16* __restrict__ Bt,
    void* __restrict__ Cout, int M, int N, int K) {
    __shared__ short sA[128 * 32];
    __shared__ short sB[128 * 32];
    const int tid = threadIdx.x;
    const int w = tid >> 6, lane = tid & 63;
    const int bn0 = blockIdx.x * 128, bm0 = blockIdx.y * 128;
    const int wr = w >> 1, wc = w & 1;

    fx4 acc[4][4];
#pragma unroll
    for (int m = 0; m < 4; ++m)
#pragma unroll
        for (int n = 0; n < 4; ++n) acc[m][n] = {0.f, 0.f, 0.f, 0.f};

    for (int k0 = 0; k0 < K; k0 += 32) {
        __syncthreads();
#pragma unroll
        for (int i = 0; i < 2; ++i) {
            int c = i * 256 + tid;
            int r = c >> 2, kk = (c & 3) * 8;
            int4 va = *(const int4*)(A + (size_t)(bm0 + r) * K + k0 + kk);
            *(int4*)(sA + c * 8) = va;
            int4 vb = *(const int4*)(Bt + (size_t)(bn0 + r) * K + k0 + kk);
            *(int4*)(sB + c * 8) = vb;
        }
        __syncthreads();
        bf16x8 af[4], bfv[4];
#pragma unroll
        for (int m = 0; m < 4; ++m)
            af[m] = *(const bf16x8*)(sA + (wr * 64 + m * 16 + (lane & 15)) * 32 + (lane >> 4) * 8);
#pragma unroll
        for (int n = 0; n < 4; ++n)
            bfv[n] = *(const bf16x8*)(sB + (wc * 64 + n * 16 + (lane & 15)) * 32 + (lane >> 4) * 8);
#pragma unroll
        for (int m = 0; m < 4; ++m)
#pragma unroll
            for (int n = 0; n < 4; ++n)
                acc[m][n] = __builtin_amdgcn_mfma_f32_16x16x32_bf16(af[m], bfv[n], acc[m][n], 0, 0, 0);
    }
#pragma unroll
    for (int m = 0; m < 4; ++m) {
        int row = bm0 + wr * 64 + m * 16 + (lane >> 4) * 4;
#pragma unroll
        for (int n = 0; n < 4; ++n) {
            int col = bn0 + wc * 64 + n * 16 + (lane & 15);
#pragma unroll
            for (int j = 0; j < 4; ++j) {
                float val = acc[m][n][j];
                if (OUT_BF16)
                    ((__hip_bfloat16*)Cout)[(size_t)(row + j) * N + col] = __float2bfloat16(val);
                else
                    ((float*)Cout)[(size_t)(row + j) * N + col] = val;
            }
        }
    }
}

// ------------------------------------- split-precision GEMM (3 bf16 products)
__global__ __launch_bounds__(256) void gemm_bt_split(
    const __hip_bfloat16* __restrict__ Ah, const __hip_bfloat16* __restrict__ Al,
    const __hip_bfloat16* __restrict__ Bth, const __hip_bfloat16* __restrict__ Btl,
    float* __restrict__ Cout, int M, int N, int K) {
    __shared__ short sAh[128 * 32];
    __shared__ short sAl[128 * 32];
    __shared__ short sBh[128 * 32];
    __shared__ short sBl[128 * 32];
    const int tid = threadIdx.x;
    const int w = tid >> 6, lane = tid & 63;
    const int bn0 = blockIdx.x * 128, bm0 = blockIdx.y * 128;
    const int wr = w >> 1, wc = w & 1;

    fx4 acc[4][4];
#pragma unroll
    for (int m = 0; m < 4; ++m)
#pragma unroll
        for (int n = 0; n < 4; ++n) acc[m][n] = {0.f, 0.f, 0.f, 0.f};

    for (int k0 = 0; k0 < K; k0 += 32) {
        __syncthreads();
#pragma unroll
        for (int i = 0; i < 2; ++i) {
            int c = i * 256 + tid;
            int r = c >> 2, kk = (c & 3) * 8;
            size_t ga = (size_t)(bm0 + r) * K + k0 + kk;
            size_t gb = (size_t)(bn0 + r) * K + k0 + kk;
            *(int4*)(sAh + c * 8) = *(const int4*)(Ah + ga);
            *(int4*)(sAl + c * 8) = *(const int4*)(Al + ga);
            *(int4*)(sBh + c * 8) = *(const int4*)(Bth + gb);
            *(int4*)(sBl + c * 8) = *(const int4*)(Btl + gb);
        }
        __syncthreads();
        bf16x8 ah[4], al[4], bh[4], bl[4];
#pragma unroll
        for (int m = 0; m < 4; ++m) {
            int off = (wr * 64 + m * 16 + (lane & 15)) * 32 + (lane >> 4) * 8;
            ah[m] = *(const bf16x8*)(sAh + off);
            al[m] = *(const bf16x8*)(sAl + off);
        }
#pragma unroll
        for (int n = 0; n < 4; ++n) {
            int off = (wc * 64 + n * 16 + (lane & 15)) * 32 + (lane >> 4) * 8;
            bh[n] = *(const bf16x8*)(sBh + off);
            bl[n] = *(const bf16x8*)(sBl + off);
        }
#pragma unroll
        for (int m = 0; m < 4; ++m)
#pragma unroll
            for (int n = 0; n < 4; ++n) {
                acc[m][n] = __builtin_amdgcn_mfma_f32_16x16x32_bf16(ah[m], bh[n], acc[m][n], 0, 0, 0);
                acc[m][n] = __builtin_amdgcn_mfma_f32_16x16x32_bf16(ah[m], bl[n], acc[m][n], 0, 0, 0);
                acc[m][n] = __builtin_amdgcn_mfma_f32_16x16x32_bf16(al[m], bh[n], acc[m][n], 0, 0, 0);
            }
    }
#pragma unroll
    for (int m = 0; m < 4; ++m) {
        int row = bm0 + wr * 64 + m * 16 + (lane >> 4) * 4;
#pragma unroll
        for (int n = 0; n < 4; ++n) {
            int col = bn0 + wc * 64 + n * 16 + (lane & 15);
#pragma unroll
            for (int j = 0; j < 4; ++j)
                Cout[(size_t)(row + j) * N + col] = acc[m][n][j];
        }
    }
}

// --------------------------------------------- RoPE + L2-normalize q,k in place
__global__ __launch_bounds__(256) void rope_kernel(float* __restrict__ X1,
                                                   const float2* __restrict__ cs) {
    int w = threadIdx.x >> 6, lane = threadIdx.x & 63;
    int p = blockIdx.x * 4 + w;            // (t,h) pair, 32768 total
    int t = p >> 4, h = p & 15;
    float2 c = cs[t * 32 + (lane & 31)];
#pragma unroll
    for (int which = 0; which < 2; ++which) {
        float* base = X1 + (size_t)t * NQKV + which * 1024 + h * 64;
        float x = base[lane];
        float xo = __shfl(x, lane ^ 32, 64);
        float r = (lane < 32) ? -xo : xo;
        float y = x * c.x + r * c.y;
        float ss = y * y;
#pragma unroll
        for (int m = 32; m; m >>= 1) ss += __shfl_xor(ss, m, 64);
        base[lane] = y * rsqrtf(ss + 1e-12f);
    }
}

// ===================== chunked delta-rule: shared helpers =====================
__device__ __forceinline__ void mm64_3p(const short* Ah, const short* Al,
                                        const short* Bh, const short* Bl,
                                        int w, int lane, fx4 acc[4]) {
#pragma unroll
    for (int k0 = 0; k0 < 64; k0 += 32) {
        int ao = (w * 16 + (lane & 15)) * LP + k0 + ((lane >> 4) * 8);
        bf16x8 ah = *(const bf16x8*)(Ah + ao);
        bf16x8 al = *(const bf16x8*)(Al + ao);
#pragma unroll
        for (int n = 0; n < 4; ++n) {
            int bo = (n * 16 + (lane & 15)) * LP + k0 + ((lane >> 4) * 8);
            bf16x8 bh = *(const bf16x8*)(Bh + bo);
            bf16x8 bl = *(const bf16x8*)(Bl + bo);
            acc[n] = __builtin_amdgcn_mfma_f32_16x16x32_bf16(ah, bh, acc[n], 0, 0, 0);
            acc[n] = __builtin_amdgcn_mfma_f32_16x16x32_bf16(ah, bl, acc[n], 0, 0, 0);
            acc[n] = __builtin_amdgcn_mfma_f32_16x16x32_bf16(al, bh, acc[n], 0, 0, 0);
        }
    }
}

__device__ __forceinline__ void split_write(short* h, short* l, int off, float x) {
    __hip_bfloat16 hb = __float2bfloat16(x);
    ((__hip_bfloat16*)h)[off] = hb;
    ((__hip_bfloat16*)l)[off] = __float2bfloat16(x - __bfloat162float(hb));
}

// ---------------------------------------------------------- phase A (parallel)
// Per (head h, chunk c): WY transform. Writes (in place over X1):
//   q-region <- Qeff = diag(gprev)Q - Ptilde*W     (f32)
//   k-region <- Olocal = Ptilde*Uv                 (f32)
// and to scratch: Ac (bf16 hi/lo), BcT (f32).
__global__ __launch_bounds__(256) void phaseA_kernel(float* __restrict__ X1,
                                                     short* __restrict__ AcBuf,
                                                     float* __restrict__ BcBuf) {
    const int h = blockIdx.x & 15, c = blockIdx.x >> 4;
    const int tid = threadIdx.x, w = tid >> 6, lane = tid & 63;
    const int t0 = c * 64;

    __shared__ float sK[4096];
    __shared__ float sM[4096];
    __shared__ float sX[64 * 128];                 // solve state, column-private
    __shared__ short b1h[64 * LP], b1l[64 * LP];   // K, later KhatT
    __shared__ short b2h[64 * LP], b2l[64 * LP];   // Q, later Ptilde
    __shared__ short b3h[64 * LP], b3l[64 * LP];   // UvT
    __shared__ short b4h[64 * LP], b4l[64 * LP];   // WT
    __shared__ float sLa[64], sB[64], sL[65], sGp[64], sRc[64];

    const float* q_g = X1 + (size_t)t0 * NQKV + h * 64;
    const float* k_g = q_g + 1024;
    const float* v_g = q_g + 2048;

    // per-step scalars: la = log(sigmoid(ga)) = -softplus(-ga); b = sigmoid(gb)
    if (tid < 64) {
        float ga = X1[(size_t)(t0 + tid) * NQKV + 4096 + h];
        float gb = X1[(size_t)(t0 + tid) * NQKV + 4112 + h];
        float z = -ga;
        sLa[tid] = -(fmaxf(z, 0.f) + log1pf(expf(-fabsf(z))));
        sB[tid] = 1.f / (1.f + expf(-gb));
    }
    __syncthreads();
    if (tid < 64) {
        // wave-parallel inclusive prefix scan of sLa
        float v = sLa[tid];
#pragma unroll
        for (int off = 1; off < 64; off <<= 1) {
            float u = __shfl_up(v, off, 64);
            if (tid >= off) v += u;
        }
        sL[tid + 1] = v;
        if (tid == 0) sL[0] = 0.f;
    }
    __syncthreads();
    if (tid < 64) {
        sGp[tid] = expf(sL[tid]);               // gamma_{t-1}
        sRc[tid] = expf(sL[64] - sL[tid + 1]);  // gammaEnd / gamma_s
    }
    // stage K (f32)
    for (int idx = tid; idx < 4096; idx += 256) {
        int r = idx >> 6, cc = idx & 63;
        sK[idx] = k_g[(size_t)r * NQKV + cc];
    }
    __syncthreads();
    // K -> buf1 (hi/lo)
    for (int idx = tid; idx < 4096; idx += 256)
        split_write(b1h, b1l, (idx >> 6) * LP + (idx & 63), sK[idx]);
    __syncthreads();

    // G = K K^T -> M (strictly lower, scaled)
    {
        fx4 acc[4];
#pragma unroll
        for (int n = 0; n < 4; ++n) acc[n] = {0.f, 0.f, 0.f, 0.f};
        mm64_3p(b1h, b1l, b1h, b1l, w, lane, acc);
#pragma unroll
        for (int n = 0; n < 4; ++n)
#pragma unroll
            for (int jj = 0; jj < 4; ++jj) {
                int t = w * 16 + (lane >> 4) * 4 + jj, s = n * 16 + (lane & 15);
                sM[t * 64 + s] = (s < t) ? sB[t] * expf(sL[t] - sL[s + 1]) * acc[n][jj] : 0.f;
            }
    }
    __syncthreads();

    // waves 0-1: forward-solve (I+M)X = [diag(b)V | diag(b*gprev)K] in LDS sX
    //   column j is private to thread j -> no barriers, no register array.
    // waves 2-3: convert Q -> buf2.
    if (w < 2) {
        const int j = tid;   // 0..127 (column of X)
        // init RHS
        for (int t = 0; t < 64; ++t)
            sX[t * 128 + j] = (j < 64) ? sB[t] * v_g[(size_t)t * NQKV + j]
                                       : sB[t] * sGp[t] * sK[t * 64 + (j - 64)];
        // forward substitution (same op order as register version)
#pragma unroll 1
        for (int t = 1; t < 64; ++t) {
            float acc = sX[t * 128 + j];
#pragma unroll 4
            for (int s = 0; s < t; ++s)
                acc = fmaf(-sM[t * 64 + s], sX[s * 128 + j], acc);
            sX[t * 128 + j] = acc;
        }
    } else {
        for (int idx = tid - 128; idx < 4096; idx += 128) {
            int r = idx >> 6, cc = idx & 63;
            split_write(b2h, b2l, r * LP + cc, q_g[(size_t)r * NQKV + cc]);
        }
    }
    __syncthreads();
    // all threads: convert sX -> UvT (b3), WT (b4)
    for (int idx = tid; idx < 8192; idx += 256) {
        int r = idx & 63, t = (idx >> 6) & 63, half = idx >> 12;
        float xv = sX[t * 128 + (half ? r + 64 : r)];
        split_write(half ? b4h : b3h, half ? b4l : b3l, r * LP + t, xv);
    }
    __syncthreads();

    // P = Q K^T
    fx4 pacc[4];
#pragma unroll
    for (int n = 0; n < 4; ++n) pacc[n] = {0.f, 0.f, 0.f, 0.f};
    mm64_3p(b2h, b2l, b1h, b1l, w, lane, pacc);
    __syncthreads();   // all reads of buf1/buf2 complete before overwrite
    // Ptilde -> buf2 (masked, scaled)
#pragma unroll
    for (int n = 0; n < 4; ++n)
#pragma unroll
        for (int jj = 0; jj < 4; ++jj) {
            int t = w * 16 + (lane >> 4) * 4 + jj, s = n * 16 + (lane & 15);
            float pv = (s < t) ? expf(sL[t] - sL[s + 1]) * pacc[n][jj] : 0.f;
            split_write(b2h, b2l, t * LP + s, pv);
        }
    // KhatT -> buf1:  [i][s] = rC[s] * K[s][i]
    for (int idx = tid; idx < 4096; idx += 256) {
        int s = idx >> 6, i = idx & 63;
        split_write(b1h, b1l, i * LP + s, sRc[s] * sK[s * 64 + i]);
    }
    __syncthreads();

    // Olocal = Ptilde @ Uv  -> overwrite k-region (f32)
    {
        fx4 acc[4];
#pragma unroll
        for (int n = 0; n < 4; ++n) acc[n] = {0.f, 0.f, 0.f, 0.f};
        mm64_3p(b2h, b2l, b3h, b3l, w, lane, acc);
        float* og = X1 + (size_t)t0 * NQKV + 1024 + h * 64;
#pragma unroll
        for (int n = 0; n < 4; ++n)
#pragma unroll
            for (int jj = 0; jj < 4; ++jj) {
                int t = w * 16 + (lane >> 4) * 4 + jj, s = n * 16 + (lane & 15);
                og[(size_t)t * NQKV + s] = acc[n][jj];
            }
    }
    // PW = Ptilde @ W ; Qeff = diag(gprev)Q - PW -> overwrite q-region (f32)
    {
        fx4 acc[4];
#pragma unroll
        for (int n = 0; n < 4; ++n) acc[n] = {0.f, 0.f, 0.f, 0.f};
        mm64_3p(b2h, b2l, b4h, b4l, w, lane, acc);
        float* qg = X1 + (size_t)t0 * NQKV + h * 64;
#pragma unroll
        for (int n = 0; n < 4; ++n)
#pragma unroll
            for (int jj = 0; jj < 4; ++jj) {
                int t = w * 16 + (lane >> 4) * 4 + jj, s = n * 16 + (lane & 15);
                float qv = qg[(size_t)t * NQKV + s];
                qg[(size_t)t * NQKV + s] = sGp[t] * qv - acc[n][jj];
            }
    }
    // Ac = gammaEnd*I - KhatT @ W  -> AcBuf (bf16 hi/lo, row-major [i][j])
    {
        fx4 acc[4];
#pragma unroll
        for (int n = 0; n < 4; ++n) acc[n] = {0.f, 0.f, 0.f, 0.f};
        mm64_3p(b1h, b1l, b4h, b4l, w, lane, acc);
        float gend = expf(sL[64]);
        size_t abase = (size_t)(h * 32 + c) * 8192;
#pragma unroll
        for (int n = 0; n < 4; ++n)
#pragma unroll
            for (int jj = 0; jj < 4; ++jj) {
                int i = w * 16 + (lane >> 4) * 4 + jj, jd = n * 16 + (lane & 15);
                float av = ((i == jd) ? gend : 0.f) - acc[n][jj];
                __hip_bfloat16 hb = __float2bfloat16(av);
                ((__hip_bfloat16*)AcBuf)[abase + i * 64 + jd] = hb;
                ((__hip_bfloat16*)AcBuf)[abase + 4096 + i * 64 + jd] =
                    __float2bfloat16(av - __bfloat162float(hb));
            }
    }
    // BcT = (KhatT @ Uv)^T = UvT @ KhatT' -> BcBuf (f32, [v][i])
    {
        fx4 acc[4];
#pragma unroll
        for (int n = 0; n < 4; ++n) acc[n] = {0.f, 0.f, 0.f, 0.f};
        mm64_3p(b3h, b3l, b1h, b1l, w, lane, acc);
        size_t bbase = (size_t)(h * 32 + c) * 4096;
#pragma unroll
        for (int n = 0; n < 4; ++n)
#pragma unroll
            for (int jj = 0; jj < 4; ++jj) {
                int jv = w * 16 + (lane >> 4) * 4 + jj, i = n * 16 + (lane & 15);
                BcBuf[bbase + jv * 64 + i] = acc[n][jj];
            }
    }
}

// --------------------------------------------------- phase B (state recurrence)
__global__ __launch_bounds__(256) void phaseB_kernel(const short* __restrict__ AcBuf,
                                                     const float* __restrict__ BcBuf,
                                                     float* __restrict__ X1) {
    const int h = blockIdx.x;
    const int tid = threadIdx.x, w = tid >> 6, lane = tid & 63;
    __shared__ float sST[4096];
    __shared__ short sSh[64 * LP], sSl[64 * LP];
    __shared__ short sAh[64 * LP], sAl[64 * LP];
    for (int idx = tid; idx < 4096; idx += 256) sST[idx] = 0.f;
    __syncthreads();
    for (int c = 0; c < 32; ++c) {
        float* stg = X1 + (size_t)(c * 64) * NQKV + 2048 + h * 64;
        for (int idx = tid; idx < 4096; idx += 256) {
            int r = idx >> 6, i = idx & 63;
            float xv = sST[idx];
            stg[(size_t)r * NQKV + i] = xv;            // state entering chunk c
            split_write(sSh, sSl, r * LP + i, xv);
        }
        const __hip_bfloat16* ag = (const __hip_bfloat16*)AcBuf + (size_t)(h * 32 + c) * 8192;
        for (int idx = tid; idx < 4096; idx += 256) {
            int r = idx >> 6, i = idx & 63;
            ((__hip_bfloat16*)sAh)[r * LP + i] = ag[idx];
            ((__hip_bfloat16*)sAl)[r * LP + i] = ag[4096 + idx];
        }
        __syncthreads();
        fx4 acc[4];
        const float* bg = BcBuf + (size_t)(h * 32 + c) * 4096;
#pragma unroll
        for (int n = 0; n < 4; ++n)
#pragma unroll
            for (int jj = 0; jj < 4; ++jj)
                acc[n][jj] = bg[(w * 16 + (lane >> 4) * 4 + jj) * 64 + n * 16 + (lane & 15)];
        mm64_3p(sSh, sSl, sAh, sAl, w, lane, acc);
#pragma unroll
        for (int n = 0; n < 4; ++n)
#pragma unroll
            for (int jj = 0; jj < 4; ++jj)
                sST[(w * 16 + (lane >> 4) * 4 + jj) * 64 + n * 16 + (lane & 15)] = acc[n][jj];
        __syncthreads();
    }
}

// --------------------------------------------- phase C (outputs + epilogue)
__global__ __launch_bounds__(256) void phaseC_kernel(const float* __restrict__ X1,
                                                     const float* __restrict__ onw,
                                                     __hip_bfloat16* __restrict__ attn_bf) {
    const int h = blockIdx.x & 15, c = blockIdx.x >> 4;
    const int tid = threadIdx.x, w = tid >> 6, lane = tid & 63;
    const int t0 = c * 64;
    __shared__ short qh[64 * LP], ql[64 * LP];
    __shared__ short sh_[64 * LP], sl_[64 * LP];
    __shared__ float sO[4096];
    __shared__ float part[64][4];
    const float* qe = X1 + (size_t)t0 * NQKV + h * 64;          // Qeff
    const float* stg = X1 + (size_t)t0 * NQKV + 2048 + h * 64;  // S^T (entering c)
    const float* ol = X1 + (size_t)t0 * NQKV + 1024 + h * 64;   // Olocal
    for (int idx = tid; idx < 4096; idx += 256) {
        int r = idx >> 6, i = idx & 63;
        split_write(qh, ql, r * LP + i, qe[(size_t)r * NQKV + i]);
        split_write(sh_, sl_, r * LP + i, stg[(size_t)r * NQKV + i]);
    }
    __syncthreads();
    fx4 acc[4];
#pragma unroll
    for (int n = 0; n < 4; ++n)
#pragma unroll
        for (int jj = 0; jj < 4; ++jj)
            acc[n][jj] = ol[(size_t)(w * 16 + (lane >> 4) * 4 + jj) * NQKV + n * 16 + (lane & 15)];
    mm64_3p(qh, ql, sh_, sl_, w, lane, acc);
#pragma unroll
    for (int n = 0; n < 4; ++n)
#pragma unroll
        for (int jj = 0; jj < 4; ++jj)
            sO[(w * 16 + (lane >> 4) * 4 + jj) * 64 + n * 16 + (lane & 15)] = acc[n][jj];
    __syncthreads();
    int r = tid >> 2, qq = tid & 3;
    float ss = 0.f;
#pragma unroll
    for (int i2 = 0; i2 < 16; ++i2) { float v = sO[r * 64 + qq * 16 + i2]; ss += v * v; }
    part[r][qq] = ss;
    __syncthreads();
    float tot = part[r][0] + part[r][1] + part[r][2] + part[r][3];
    float sc = rsqrtf(tot * (1.f / 64.f) + 1e-6f);
    const float* gg = X1 + (size_t)(t0 + r) * NQKV + 3072 + h * 64;
#pragma unroll
    for (int i2 = 0; i2 < 16; ++i2) {
        int j = qq * 16 + i2;
        float on = sO[r * 64 + j] * sc * onw[j];
        float g = gg[j];
        float sg = g / (1.f + expf(-g));
        attn_bf[(size_t)(t0 + r) * 1024 + h * 64 + j] = __float2bfloat16(on * sg);
    }
}

// ---------------------------- h = hidden + attn (in place); ybf = rmsnorm(h)
__global__ __launch_bounds__(256) void add_rmsnorm_kernel(
    const float* __restrict__ hidden, float* __restrict__ acc,
    const float* __restrict__ w, __hip_bfloat16* __restrict__ out) {
    int t = blockIdx.x;
    int d = threadIdx.x * 4;
    float4 a = *(const float4*)(acc + (size_t)t * D_MODEL + d);
    float4 hd = *(const float4*)(hidden + (size_t)t * D_MODEL + d);
    float4 h4 = make_float4(a.x + hd.x, a.y + hd.y, a.z + hd.z, a.w + hd.w);
    *(float4*)(acc + (size_t)t * D_MODEL + d) = h4;
    float ss = h4.x * h4.x + h4.y * h4.y + h4.z * h4.z + h4.w * h4.w;
#pragma unroll
    for (int m = 32; m; m >>= 1) ss += __shfl_xor(ss, m, 64);
    __shared__ float wsum[4];
    if ((threadIdx.x & 63) == 0) wsum[threadIdx.x >> 6] = ss;
    __syncthreads();
    float tot = wsum[0] + wsum[1] + wsum[2] + wsum[3];
    float sc = rsqrtf(tot * (1.f / 1024.f) + 1e-6f);
    const float4 wv = *(const float4*)(w + d);
    __hip_bfloat16* op = out + (size_t)t * D_MODEL + d;
    op[0] = __float2bfloat16(h4.x * sc * wv.x);
    op[1] = __float2bfloat16(h4.y * sc * wv.y);
    op[2] = __float2bfloat16(h4.z * sc * wv.z);
    op[3] = __float2bfloat16(h4.w * sc * wv.w);
}

// ---------------------------------------------- m = silu(G) * U (bf16 in/out)
__global__ __launch_bounds__(256) void silu_mul_kernel(const __hip_bfloat16* __restrict__ GU,
                                                       __hip_bfloat16* __restrict__ m) {
    size_t i = (size_t)blockIdx.x * 256 + threadIdx.x;   // 2048*4096
    size_t t = i >> 12, j = i & 4095;
    float g = __bfloat162float(GU[t * 8192 + j]);
    float u = __bfloat162float(GU[t * 8192 + 4096 + j]);
    m[i] = __float2bfloat16(u * g / (1.f + expf(-g)));
}

// ----------------------------------------------------------- out += h
__global__ __launch_bounds__(256) void final_add_kernel(float* __restrict__ out,
                                                        const float* __restrict__ h) {
    size_t i = (size_t)blockIdx.x * 256 + threadIdx.x;
    out[i] += h[i];
}

// ---------------------------------------------------------------------------
extern "C" void kernel_launch(void* const* d_in, const int* in_sizes, int n_in,
                              void* d_out, int out_size, void* d_ws, size_t ws_size,
                              hipStream_t stream) {
    (void)in_sizes; (void)n_in; (void)out_size; (void)ws_size;
    const float* hidden     = (const float*)d_in[0];
    const float* norm1_w    = (const float*)d_in[1];
    const float* q_w        = (const float*)d_in[2];
    const float* k_w        = (const float*)d_in[3];
    const float* v_w        = (const float*)d_in[4];
    const float* g_w        = (const float*)d_in[5];
    const float* b_w        = (const float*)d_in[6];
    const float* gate_w     = (const float*)d_in[7];
    const float* o_norm_w   = (const float*)d_in[8];
    const float* o_w        = (const float*)d_in[9];
    const float* norm2_w    = (const float*)d_in[10];
    const float* mlp_gate_w = (const float*)d_in[11];
    const float* mlp_up_w   = (const float*)d_in[12];
    const float* mlp_down_w = (const float*)d_in[13];

    char* ws = (char*)d_ws;
    // workspace (~92 MiB), timeline-reused:
    const size_t OFF_WT_QKVG = 0;          // wt_qkvg_hi -> AcBuf (phase A/B)
    const size_t OFF_WT_O    = 8650752;
    const size_t OFF_WT_GU   = 10747904;
    const size_t OFF_WT_DOWN = 27525120;
    const size_t OFF_X1      = 35913728;   // X1 f32 (q->Qeff, k->Olocal, v->S states) -> GU bf16
    const size_t OFF_R1      = 70516736;   // wt_qkvg_lo -> BcBuf -> mbf
    const size_t OFF_ATTN    = 79167488;
    const size_t OFF_YBF     = 83361792;
    const size_t OFF_XHI     = 87556096;   // xhi/xlo -> h_buf
    const size_t OFF_XLO     = 91750400;
    const size_t OFF_ROPE    = 95944704;

    __hip_bfloat16* wt_qkvg_hi = (__hip_bfloat16*)(ws + OFF_WT_QKVG);
    __hip_bfloat16* wt_qkvg_lo = (__hip_bfloat16*)(ws + OFF_R1);
    __hip_bfloat16* wt_o    = (__hip_bfloat16*)(ws + OFF_WT_O);
    __hip_bfloat16* wt_gu   = (__hip_bfloat16*)(ws + OFF_WT_GU);
    __hip_bfloat16* wt_down = (__hip_bfloat16*)(ws + OFF_WT_DOWN);
    float*          X1      = (float*)(ws + OFF_X1);
    __hip_bfloat16* GU      = (__hip_bfloat16*)(ws + OFF_X1);
    short*          AcBuf   = (short*)(ws + OFF_WT_QKVG);       // after qkv gemm
    float*          BcBuf   = (float*)(ws + OFF_R1);            // after qkv gemm
    __hip_bfloat16* mbf     = (__hip_bfloat16*)(ws + OFF_R1);   // after phase B/C
    __hip_bfloat16* attn_bf = (__hip_bfloat16*)(ws + OFF_ATTN);
    __hip_bfloat16* xhi     = (__hip_bfloat16*)(ws + OFF_XHI);
    __hip_bfloat16* xlo     = (__hip_bfloat16*)(ws + OFF_XLO);
    float*          h_buf   = (float*)(ws + OFF_XHI);
    __hip_bfloat16* ybf     = (__hip_bfloat16*)(ws + OFF_YBF);
    float2*         rope_cs = (float2*)(ws + OFF_ROPE);

    dim3 tb(32, 8);
    rope_table_kernel<<<256, 256, 0, stream>>>(rope_cs);
    rmsnorm_split_kernel<<<2048, 256, 0, stream>>>(hidden, norm1_w, xhi, xlo);
    transpose_split_kernel<<<dim3(32, 32), tb, 0, stream>>>(q_w,    wt_qkvg_hi,               wt_qkvg_lo,               1024, 1024, 1024);
    transpose_split_kernel<<<dim3(32, 32), tb, 0, stream>>>(k_w,    wt_qkvg_hi + 1024 * 1024, wt_qkvg_lo + 1024 * 1024, 1024, 1024, 1024);
    transpose_split_kernel<<<dim3(32, 32), tb, 0, stream>>>(v_w,    wt_qkvg_hi + 2048 * 1024, wt_qkvg_lo + 2048 * 1024, 1024, 1024, 1024);
    transpose_split_kernel<<<dim3(32, 32), tb, 0, stream>>>(gate_w, wt_qkvg_hi + 3072 * 1024, wt_qkvg_lo + 3072 * 1024, 1024, 1024, 1024);
    transpose_split_kernel<<<dim3(32, 1),  tb, 0, stream>>>(g_w,    wt_qkvg_hi + 4096 * 1024, wt_qkvg_lo + 4096 * 1024, 1024, 16,   16);
    transpose_split_kernel<<<dim3(32, 4),  tb, 0, stream>>>(b_w,    wt_qkvg_hi + 4112 * 1024, wt_qkvg_lo + 4112 * 1024, 1024, 16,   112);
    transpose_bf16_kernel<<<dim3(32, 32),  tb, 0, stream>>>(o_w,        wt_o,                1024, 1024, 1024);
    transpose_bf16_kernel<<<dim3(32, 128), tb, 0, stream>>>(mlp_gate_w, wt_gu,               1024, 4096, 4096);
    transpose_bf16_kernel<<<dim3(32, 128), tb, 0, stream>>>(mlp_up_w,   wt_gu + 4096 * 1024, 1024, 4096, 4096);
    transpose_bf16_kernel<<<dim3(128, 32), tb, 0, stream>>>(mlp_down_w, wt_down,             4096, 1024, 1024);
    // fused q|k|v|gate|g|b projection (split precision)
    gemm_bt_split<<<dim3(33, 16), 256, 0, stream>>>(xhi, xlo, wt_qkvg_hi, wt_qkvg_lo, X1, 2048, NQKV, 1024);
    rope_kernel<<<8192, 256, 0, stream>>>(X1, rope_cs);
    // chunked delta-rule scan
    phaseA_kernel<<<512, 256, 0, stream>>>(X1, AcBuf, BcBuf);
    phaseB_kernel<<<16, 256, 0, stream>>>(AcBuf, BcBuf, X1);
    phaseC_kernel<<<512, 256, 0, stream>>>(X1, o_norm_w, attn_bf);
    // attn out projection -> h
    gemm_bt<false><<<dim3(8, 16), 256, 0, stream>>>(attn_bf, wt_o, h_buf, 2048, 1024, 1024);
    add_rmsnorm_kernel<<<2048, 256, 0, stream>>>(hidden, h_buf, norm2_w, ybf);
    gemm_bt<true><<<dim3(64, 16), 256, 0, stream>>>(ybf, wt_gu, GU, 2048, 8192, 1024);
    silu_mul_kernel<<<32768, 256, 0, stream>>>(GU, mbf);
    gemm_bt<false><<<dim3(8, 16), 256, 0, stream>>>(mbf, wt_down, (float*)d_out, 2048, 1024, 4096);
    final_add_kernel<<<8192, 256, 0, stream>>>((float*)d_out, h_buf);
}